// Round 2
// baseline (1492.583 us; speedup 1.0000x reference)
//
#include <hip/hip_runtime.h>
#include <hip/hip_bf16.h>
#include <math.h>

// Problem constants
#define B_   2
#define N_   8192
#define DM   768
#define NH   12
#define HD   64

// Workspace layout (in floats):
//   Q   at 0          size 2*8192*768 = 12,582,912   (reused as OLN later)
//   AC  at 12,582,912 size 7,340,032  (compact per-group attention out)
//   SUMS at 19,922,944 size 3*2*256 = 1536
#define Q_OFF    0ull
#define AC_OFF   12582912ull
#define SUMS_OFF 19922944ull

// group base within AC: 0, 4194304, 6291456
__device__ __forceinline__ size_t ac_base(int grp) {
    return 8388608ull - (8388608ull >> grp);
}

__device__ __forceinline__ void fma4(float4& a, float s, const float4& b) {
    a.x = fmaf(s, b.x, a.x);
    a.y = fmaf(s, b.y, a.y);
    a.z = fmaf(s, b.z, a.z);
    a.w = fmaf(s, b.w, a.w);
}

// ---------------------------------------------------------------------------
// GEMM (NT): C[m,n] = sum_k A[m,k]*Bw[n,k] + bias[n].  M%128==0, N%128==0, K%16==0
// 128x128 tile, 256 threads, 8x8 per thread in 2x2 sub-blocks of 4x4.
// ---------------------------------------------------------------------------
__global__ __launch_bounds__(256) void gemm_nt_bias(
    const float* __restrict__ A, const float* __restrict__ Bw,
    const float* __restrict__ bias, float* __restrict__ C,
    int M, int N, int K) {
    __shared__ float As[16][132];
    __shared__ float Bs[16][132];

    const int t  = threadIdx.x;
    const int tx = t & 15, ty = t >> 4;
    const int m0 = blockIdx.x * 128, n0 = blockIdx.y * 128;
    const int lrow = t >> 1;          // 0..127
    const int lk   = (t & 1) * 8;     // 0 or 8

    const float* ap = A  + (size_t)(m0 + lrow) * K + lk;
    const float* bp = Bw + (size_t)(n0 + lrow) * K + lk;

    float4 acc[2][2][4];
#pragma unroll
    for (int mh = 0; mh < 2; ++mh)
#pragma unroll
        for (int nh = 0; nh < 2; ++nh)
#pragma unroll
            for (int i = 0; i < 4; ++i)
                acc[mh][nh][i] = make_float4(0.f, 0.f, 0.f, 0.f);

    for (int k0 = 0; k0 < K; k0 += 16) {
        float4 a0 = *(const float4*)(ap + k0);
        float4 a1 = *(const float4*)(ap + k0 + 4);
        float4 b0 = *(const float4*)(bp + k0);
        float4 b1 = *(const float4*)(bp + k0 + 4);
        __syncthreads();
        As[lk+0][lrow] = a0.x; As[lk+1][lrow] = a0.y;
        As[lk+2][lrow] = a0.z; As[lk+3][lrow] = a0.w;
        As[lk+4][lrow] = a1.x; As[lk+5][lrow] = a1.y;
        As[lk+6][lrow] = a1.z; As[lk+7][lrow] = a1.w;
        Bs[lk+0][lrow] = b0.x; Bs[lk+1][lrow] = b0.y;
        Bs[lk+2][lrow] = b0.z; Bs[lk+3][lrow] = b0.w;
        Bs[lk+4][lrow] = b1.x; Bs[lk+5][lrow] = b1.y;
        Bs[lk+6][lrow] = b1.z; Bs[lk+7][lrow] = b1.w;
        __syncthreads();
#pragma unroll
        for (int kk = 0; kk < 16; ++kk) {
            float4 av0 = *(const float4*)&As[kk][ty*4];
            float4 av1 = *(const float4*)&As[kk][64 + ty*4];
            float4 bv0 = *(const float4*)&Bs[kk][tx*4];
            float4 bv1 = *(const float4*)&Bs[kk][64 + tx*4];
            const float am[8] = {av0.x, av0.y, av0.z, av0.w,
                                 av1.x, av1.y, av1.z, av1.w};
#pragma unroll
            for (int i = 0; i < 4; ++i) {
                fma4(acc[0][0][i], am[i],   bv0);
                fma4(acc[0][1][i], am[i],   bv1);
                fma4(acc[1][0][i], am[4+i], bv0);
                fma4(acc[1][1][i], am[4+i], bv1);
            }
        }
    }

#pragma unroll
    for (int mh = 0; mh < 2; ++mh)
#pragma unroll
        for (int i = 0; i < 4; ++i) {
            const int row = m0 + mh*64 + ty*4 + i;
            float* crow = C + (size_t)row * N;
#pragma unroll
            for (int nh = 0; nh < 2; ++nh) {
                const int col = n0 + nh*64 + tx*4;
                float4 bb = *(const float4*)(bias + col);
                float4 r = acc[mh][nh][i];
                r.x += bb.x; r.y += bb.y; r.z += bb.z; r.w += bb.w;
                *(float4*)(crow + col) = r;
            }
        }
}

// ---------------------------------------------------------------------------
// Flash attention over one (b, group, segment, head), Q=K=V.
// Q-tile 64 x 64(d), K-tile 64. 256 threads as a 16x16 grid: thread (tx,ty)
// owns score rows ty*4..+3 (queries) x cols tx*4..+3 (keys) -> 4x4 scores,
// and output rows ty*4..+3 x dims tx*4..+3.
// kst_ps: K-tile transposed [d][k] during the score phase, then reused as
// P [q][k] for the PV phase (barriers separate the two uses).
// Output (softmax @ V, un-renormalized) written compact to AC.
// ---------------------------------------------------------------------------
__global__ __launch_bounds__(256) void attn_kernel(
    const float* __restrict__ Q, float* __restrict__ AC) {
    __shared__ float qs[64][68];
    __shared__ float ks[64][68];
    __shared__ float kst_ps[64][68];

    const int t  = threadIdx.x;
    const int tx = t & 15, ty = t >> 4;

    const int bi  = blockIdx.x;
    const int qt  = bi & 31;
    const int bsh = bi >> 5;
    int grp, local;
    if (bsh < 32)      { grp = 0; local = bsh; }
    else if (bsh < 48) { grp = 1; local = bsh - 32; }
    else               { grp = 2; local = bsh - 48; }
    const int nseg = 4 >> grp;
    const int sseg = 2048 << grp;
    const int r    = 1 << grp;
    const int b    = local / (nseg * 4);
    const int rem  = local - b * nseg * 4;
    const int seg  = rem >> 2;
    const int hg   = rem & 3;
    const int head = grp * 4 + hg;

    const float* qb = Q + ((size_t)(b * N_ + seg * sseg + grp)) * DM + head * HD;
    const size_t rstride = (size_t)r * DM;

    // load Q tile (queries qt*64..+63)
    {
        const int row = t >> 2, c4 = t & 3;
        const float4* src = (const float4*)(qb + (size_t)(qt*64 + row) * rstride);
#pragma unroll
        for (int i = 0; i < 4; ++i) {
            float4 v = src[c4 + 4*i];
            *(float4*)&qs[row][(c4 + 4*i)*4] = v;
        }
    }

    float  m_i[4], l_i[4];
    float4 o[4];
#pragma unroll
    for (int i = 0; i < 4; ++i) {
        m_i[i] = -1e30f; l_i[i] = 0.f;
        o[i] = make_float4(0.f, 0.f, 0.f, 0.f);
    }

    for (int kt = 0; kt < 32; ++kt) {
        __syncthreads();   // previous iteration's readers done with ks/kst_ps
        {
            const int row = t >> 2, c4 = t & 3;
            const float4* src = (const float4*)(qb + (size_t)(kt*64 + row) * rstride);
#pragma unroll
            for (int i = 0; i < 4; ++i) {
                float4 v = src[c4 + 4*i];
                *(float4*)&ks[row][(c4 + 4*i)*4] = v;
                const int d0 = (c4 + 4*i)*4;
                kst_ps[d0+0][row] = v.x;
                kst_ps[d0+1][row] = v.y;
                kst_ps[d0+2][row] = v.z;
                kst_ps[d0+3][row] = v.w;
            }
        }
        __syncthreads();

        // ---- scores: S[i][j] = sum_d q[ty*4+i][d] * k[tx*4+j][d]
        float sc[16];
#pragma unroll
        for (int z = 0; z < 16; ++z) sc[z] = 0.f;
#pragma unroll 4
        for (int d4 = 0; d4 < 16; ++d4) {
            float qreg[16];
#pragma unroll
            for (int i = 0; i < 4; ++i) {
                float4 v = *(const float4*)&qs[ty*4 + i][d4*4];
                qreg[i*4+0] = v.x; qreg[i*4+1] = v.y;
                qreg[i*4+2] = v.z; qreg[i*4+3] = v.w;
            }
#pragma unroll
            for (int c = 0; c < 4; ++c) {
                float4 kv = *(const float4*)&kst_ps[d4*4 + c][tx*4];
#pragma unroll
                for (int i = 0; i < 4; ++i) {
                    const float qv = qreg[i*4 + c];
                    sc[i*4+0] = fmaf(qv, kv.x, sc[i*4+0]);
                    sc[i*4+1] = fmaf(qv, kv.y, sc[i*4+1]);
                    sc[i*4+2] = fmaf(qv, kv.z, sc[i*4+2]);
                    sc[i*4+3] = fmaf(qv, kv.w, sc[i*4+3]);
                }
            }
        }
#pragma unroll
        for (int z = 0; z < 16; ++z) sc[z] *= 0.125f;  // 1/sqrt(64)

        // everyone done reading kst_ps (K^T) before it is overwritten with P
        __syncthreads();

        // ---- online softmax (each score row spread across the 16 tx lanes)
#pragma unroll
        for (int i = 0; i < 4; ++i) {
            float rm = fmaxf(fmaxf(sc[i*4+0], sc[i*4+1]),
                             fmaxf(sc[i*4+2], sc[i*4+3]));
            rm = fmaxf(rm, __shfl_xor(rm, 1));
            rm = fmaxf(rm, __shfl_xor(rm, 2));
            rm = fmaxf(rm, __shfl_xor(rm, 4));
            rm = fmaxf(rm, __shfl_xor(rm, 8));
            const float mnew  = fmaxf(m_i[i], rm);
            const float alpha = __expf(m_i[i] - mnew);
            m_i[i] = mnew;
            float p0 = __expf(sc[i*4+0] - mnew);
            float p1 = __expf(sc[i*4+1] - mnew);
            float p2 = __expf(sc[i*4+2] - mnew);
            float p3 = __expf(sc[i*4+3] - mnew);
            float psum = p0 + p1 + p2 + p3;
            psum += __shfl_xor(psum, 1);
            psum += __shfl_xor(psum, 2);
            psum += __shfl_xor(psum, 4);
            psum += __shfl_xor(psum, 8);
            l_i[i] = l_i[i] * alpha + psum;
            o[i].x *= alpha; o[i].y *= alpha; o[i].z *= alpha; o[i].w *= alpha;
            *(float4*)&kst_ps[ty*4 + i][tx*4] = make_float4(p0, p1, p2, p3);
        }
        __syncthreads();   // P fully visible before PV reads

        // ---- PV: O[q][d] += sum_k P[q][k] * V[k][d]
#pragma unroll 4
        for (int k4 = 0; k4 < 16; ++k4) {
            float preg[16];
#pragma unroll
            for (int i = 0; i < 4; ++i) {
                float4 v = *(const float4*)&kst_ps[ty*4 + i][k4*4];
                preg[i*4+0] = v.x; preg[i*4+1] = v.y;
                preg[i*4+2] = v.z; preg[i*4+3] = v.w;
            }
#pragma unroll
            for (int c = 0; c < 4; ++c) {
                float4 vv = *(const float4*)&ks[k4*4 + c][tx*4];
#pragma unroll
                for (int i = 0; i < 4; ++i) {
                    fma4(o[i], preg[i*4 + c], vv);
                }
            }
        }
    }

    // epilogue: divide by l, write compact AC
    const size_t gbase = ac_base(grp);
#pragma unroll
    for (int i = 0; i < 4; ++i) {
        const float inv = 1.0f / l_i[i];
        const int q = qt*64 + ty*4 + i;
        float* dst = AC + gbase + ((size_t)((b*nseg + seg)*2048 + q)) * 256 + hg*64;
        *(float4*)(dst + tx*4) =
            make_float4(o[i].x*inv, o[i].y*inv, o[i].z*inv, o[i].w*inv);
    }
}

// ---------------------------------------------------------------------------
// Per-(group,b,head-in-group,d) sums over all positions (the x/x.sum renorm).
// SUMS must be zeroed first. 112 blocks: g0 2*32, g1 2*16, g2 2*8 chunks.
// ---------------------------------------------------------------------------
__global__ __launch_bounds__(256) void sum_kernel(
    const float* __restrict__ AC, float* __restrict__ SUMS) {
    const int bi = blockIdx.x;
    int grp, local;
    if (bi < 64)      { grp = 0; local = bi; }
    else if (bi < 96) { grp = 1; local = bi - 64; }
    else              { grp = 2; local = bi - 96; }
    const int chunks = 32 >> grp;
    const int b  = local / chunks;
    const int ch = local - b * chunks;
    const int P  = 8192 >> grp;   // positions per batch in this group
    const size_t base = ac_base(grp) + ((size_t)b * P + ch * 256) * 256 + threadIdx.x;
    float acc = 0.f;
    for (int p = 0; p < 256; ++p) acc += AC[base + (size_t)p * 256];
    atomicAdd(&SUMS[((grp << 1) + b) * 256 + threadIdx.x], acc);
}

// ---------------------------------------------------------------------------
// Renormalize + scatter (zeros at non-selected positions) + /3 + LayerNorm
// One block per (b, n) position, 256 threads x 3 dims.
// ---------------------------------------------------------------------------
__device__ __forceinline__ float block_reduce_sum(float val, float* sdata) {
    __syncthreads();
#pragma unroll
    for (int o = 32; o > 0; o >>= 1) val += __shfl_down(val, o);
    const int lane = threadIdx.x & 63, wid = threadIdx.x >> 6;
    if (lane == 0) sdata[wid] = val;
    __syncthreads();
    return sdata[0] + sdata[1] + sdata[2] + sdata[3];
}

__global__ __launch_bounds__(256) void renorm_ln_kernel(
    const float* __restrict__ AC, const float* __restrict__ SUMS,
    const float* __restrict__ gamma, const float* __restrict__ beta,
    float* __restrict__ OLN) {
    __shared__ float sdata[4];
    const int pos = blockIdx.x;
    const int b = pos >> 13;
    const int n = pos & 8191;

    float v[3];
    int dms[3];
#pragma unroll
    for (int jj = 0; jj < 3; ++jj) {
        const int dm = threadIdx.x + (jj << 8);
        dms[jj] = dm;
        const int h = dm >> 6, d = dm & 63;
        const int grp = h >> 2, hg = h & 3;
        const int r = 1 << grp;
        const int p = n & ((2048 << grp) - 1);
        float val = 0.f;
        if ((p & (r - 1)) == grp) {
            const int nseg = 4 >> grp;
            const int seg  = n >> (11 + grp);
            const int j    = (p - grp) >> grp;
            const float s  = SUMS[((grp << 1) + b) * 256 + (hg << 6) + d];
            val = AC[ac_base(grp) + ((size_t)((b*nseg + seg)*2048 + j)) * 256 + (hg << 6) + d]
                  / (3.0f * s);
        }
        v[jj] = val;
    }

    const float tot = block_reduce_sum(v[0] + v[1] + v[2], sdata);
    const float mu  = tot * (1.0f / 768.0f);
    float sq = 0.f;
#pragma unroll
    for (int jj = 0; jj < 3; ++jj) {
        const float d0 = v[jj] - mu;
        sq += d0 * d0;
    }
    const float var  = block_reduce_sum(sq, sdata) * (1.0f / 768.0f);
    const float rstd = rsqrtf(var + 1e-5f);

    float* dst = OLN + (size_t)pos * 768;
#pragma unroll
    for (int jj = 0; jj < 3; ++jj)
        dst[dms[jj]] = (v[jj] - mu) * rstd * gamma[dms[jj]] + beta[dms[jj]];
}

// ---------------------------------------------------------------------------
extern "C" void kernel_launch(void* const* d_in, const int* in_sizes, int n_in,
                              void* d_out, int out_size, void* d_ws, size_t ws_size,
                              hipStream_t stream) {
    const float* x     = (const float*)d_in[0];
    const float* w_in  = (const float*)d_in[1];
    const float* b_in  = (const float*)d_in[2];
    const float* w_out = (const float*)d_in[3];
    const float* b_out = (const float*)d_in[4];
    const float* gamma = (const float*)d_in[5];
    const float* beta  = (const float*)d_in[6];
    float* out = (float*)d_out;

    float* ws   = (float*)d_ws;
    float* Q    = ws + Q_OFF;
    float* AC   = ws + AC_OFF;
    float* SUMS = ws + SUMS_OFF;
    float* OLN  = ws + Q_OFF;   // reuse Q region (dead after attention)

    // 1) Q = x @ w_in.T + b_in
    gemm_nt_bias<<<dim3(128, 6), 256, 0, stream>>>(x, w_in, b_in, Q,
                                                   B_ * N_, DM, DM);
    // 2) dilated flash attention (compact per-group output)
    attn_kernel<<<1792, 256, 0, stream>>>(Q, AC);
    // 3) per-(group,b,h,d) position sums for the x/x.sum renorm
    hipMemsetAsync(SUMS, 0, 1536 * sizeof(float), stream);
    sum_kernel<<<112, 256, 0, stream>>>(AC, SUMS);
    // 4) renorm + scatter + /3 + LayerNorm
    renorm_ln_kernel<<<B_ * N_, 256, 0, stream>>>(AC, SUMS, gamma, beta, OLN);
    // 5) out = OLN @ w_out.T + b_out
    gemm_nt_bias<<<dim3(128, 6), 256, 0, stream>>>(OLN, w_out, b_out, out,
                                                   B_ * N_, DM, DM);
}

// Round 3
// 1176.215 us; speedup vs baseline: 1.2690x; 1.2690x over previous
//
#include <hip/hip_runtime.h>
#include <hip/hip_bf16.h>
#include <math.h>

// Problem constants
#define B_   2
#define N_   8192
#define DM   768
#define NH   12
#define HD   64

// Workspace layout (in floats):
//   Q   at 0          size 2*8192*768 = 12,582,912   (reused as OLN later)
//   AC  at 12,582,912 size 7,340,032  (compact per-group attention out)
//   SUMS at 19,922,944 size 3*2*256 = 1536
#define Q_OFF    0ull
#define AC_OFF   12582912ull
#define SUMS_OFF 19922944ull

typedef short bf16x8 __attribute__((ext_vector_type(8)));
typedef float f32x4  __attribute__((ext_vector_type(4)));

// group base within AC: 0, 4194304, 6291456
__device__ __forceinline__ size_t ac_base(int grp) {
    return 8388608ull - (8388608ull >> grp);
}

__device__ __forceinline__ void fma4(float4& a, float s, const float4& b) {
    a.x = fmaf(s, b.x, a.x);
    a.y = fmaf(s, b.y, a.y);
    a.z = fmaf(s, b.z, a.z);
    a.w = fmaf(s, b.w, a.w);
}

__device__ __forceinline__ unsigned short f2bf(float f) {
    __hip_bfloat16 h = __float2bfloat16(f);
    return __builtin_bit_cast(unsigned short, h);
}
__device__ __forceinline__ float bf2f(unsigned short u) {
    __hip_bfloat16 h = __builtin_bit_cast(__hip_bfloat16, u);
    return __bfloat162float(h);
}

// ---------------------------------------------------------------------------
// Split-bf16 MFMA GEMM (NT): C[m,n] = sum_k A[m,k]*W[n,k] + bias[n]
// A,W fp32 in global; staged to LDS as bf16 hi+lo pairs. Per-product:
// D ~= AhiBhi + AhiBlo + AloBhi  (error ~2^-17 relative, fp32-class).
// M = grid.x*128, N = grid.y*128 (=768), K = 768. 256 threads, 4 waves,
// each wave computes 64x64 via 4x4 tiles of mfma_f32_16x16x32_bf16.
// Fragment layouts (gfx950, HW-verified per guide):
//   A-operand: m = lane&15, k = (lane>>4)*8 + j   (8 contiguous bf16)
//   B-operand: n = lane&15, k = (lane>>4)*8 + j
//   C/D:       col = lane&15, row = (lane>>4)*4 + reg
// ---------------------------------------------------------------------------
__global__ __launch_bounds__(256) void gemm_mfma_split(
    const float* __restrict__ A, const float* __restrict__ W,
    const float* __restrict__ bias, float* __restrict__ C) {
    __shared__ unsigned short AsH[128][40];  // pitch 40 -> bank-uniform frag reads
    __shared__ unsigned short AsL[128][40];
    __shared__ unsigned short WsH[128][40];
    __shared__ unsigned short WsL[128][40];

    const int t    = threadIdx.x;
    const int lane = t & 63;
    const int wv   = t >> 6;
    const int c    = lane & 15, q = lane >> 4;
    const int mw   = (wv & 1) * 64, nw = (wv >> 1) * 64;
    const int m0   = blockIdx.x * 128, n0 = blockIdx.y * 128;

    const int srow = t >> 1;          // 0..127
    const int scol = (t & 1) * 16;    // 0 or 16
    const float* ap = A + (size_t)(m0 + srow) * DM + scol;
    const float* wp = W + (size_t)(n0 + srow) * DM + scol;

    f32x4 acc[4][4];
#pragma unroll
    for (int mi = 0; mi < 4; ++mi)
#pragma unroll
        for (int ni = 0; ni < 4; ++ni) {
            acc[mi][ni][0] = 0.f; acc[mi][ni][1] = 0.f;
            acc[mi][ni][2] = 0.f; acc[mi][ni][3] = 0.f;
        }

    for (int k0 = 0; k0 < DM; k0 += 32) {
        float av[16], wvv[16];
        *(float4*)&av[0]  = *(const float4*)(ap + k0);
        *(float4*)&av[4]  = *(const float4*)(ap + k0 + 4);
        *(float4*)&av[8]  = *(const float4*)(ap + k0 + 8);
        *(float4*)&av[12] = *(const float4*)(ap + k0 + 12);
        *(float4*)&wvv[0]  = *(const float4*)(wp + k0);
        *(float4*)&wvv[4]  = *(const float4*)(wp + k0 + 4);
        *(float4*)&wvv[8]  = *(const float4*)(wp + k0 + 8);
        *(float4*)&wvv[12] = *(const float4*)(wp + k0 + 12);
        __syncthreads();   // previous iteration's frag readers done
#pragma unroll
        for (int i = 0; i < 16; ++i) {
            const float x = av[i];
            const unsigned short xh = f2bf(x);
            AsH[srow][scol + i] = xh;
            AsL[srow][scol + i] = f2bf(x - bf2f(xh));
            const float y = wvv[i];
            const unsigned short yh = f2bf(y);
            WsH[srow][scol + i] = yh;
            WsL[srow][scol + i] = f2bf(y - bf2f(yh));
        }
        __syncthreads();

        bf16x8 ah[4], al[4], bh[4], bl[4];
#pragma unroll
        for (int i = 0; i < 4; ++i) {
            ah[i] = *(const bf16x8*)&AsH[mw + i*16 + c][q*8];
            al[i] = *(const bf16x8*)&AsL[mw + i*16 + c][q*8];
            bh[i] = *(const bf16x8*)&WsH[nw + i*16 + c][q*8];
            bl[i] = *(const bf16x8*)&WsL[nw + i*16 + c][q*8];
        }
#pragma unroll
        for (int mi = 0; mi < 4; ++mi)
#pragma unroll
            for (int ni = 0; ni < 4; ++ni) {
                f32x4 v = acc[mi][ni];
                v = __builtin_amdgcn_mfma_f32_16x16x32_bf16(ah[mi], bl[ni], v, 0, 0, 0);
                v = __builtin_amdgcn_mfma_f32_16x16x32_bf16(al[mi], bh[ni], v, 0, 0, 0);
                v = __builtin_amdgcn_mfma_f32_16x16x32_bf16(ah[mi], bh[ni], v, 0, 0, 0);
                acc[mi][ni] = v;
            }
    }

    // epilogue: add bias, store fp32
#pragma unroll
    for (int ni = 0; ni < 4; ++ni) {
        const int col = n0 + nw + ni*16 + c;
        const float bv = bias[col];
#pragma unroll
        for (int mi = 0; mi < 4; ++mi)
#pragma unroll
            for (int r = 0; r < 4; ++r) {
                const int row = m0 + mw + mi*16 + q*4 + r;
                C[(size_t)row * DM + col] = acc[mi][ni][r] + bv;
            }
    }
}

// ---------------------------------------------------------------------------
// Flash attention over one (b, group, segment, head), Q=K=V. (unchanged, R2)
// ---------------------------------------------------------------------------
__global__ __launch_bounds__(256) void attn_kernel(
    const float* __restrict__ Q, float* __restrict__ AC) {
    __shared__ float qs[64][68];
    __shared__ float ks[64][68];
    __shared__ float kst_ps[64][68];

    const int t  = threadIdx.x;
    const int tx = t & 15, ty = t >> 4;

    const int bi  = blockIdx.x;
    const int qt  = bi & 31;
    const int bsh = bi >> 5;
    int grp, local;
    if (bsh < 32)      { grp = 0; local = bsh; }
    else if (bsh < 48) { grp = 1; local = bsh - 32; }
    else               { grp = 2; local = bsh - 48; }
    const int nseg = 4 >> grp;
    const int sseg = 2048 << grp;
    const int r    = 1 << grp;
    const int b    = local / (nseg * 4);
    const int rem  = local - b * nseg * 4;
    const int seg  = rem >> 2;
    const int hg   = rem & 3;
    const int head = grp * 4 + hg;

    const float* qb = Q + ((size_t)(b * N_ + seg * sseg + grp)) * DM + head * HD;
    const size_t rstride = (size_t)r * DM;

    {
        const int row = t >> 2, c4 = t & 3;
        const float4* src = (const float4*)(qb + (size_t)(qt*64 + row) * rstride);
#pragma unroll
        for (int i = 0; i < 4; ++i) {
            float4 v = src[c4 + 4*i];
            *(float4*)&qs[row][(c4 + 4*i)*4] = v;
        }
    }

    float  m_i[4], l_i[4];
    float4 o[4];
#pragma unroll
    for (int i = 0; i < 4; ++i) {
        m_i[i] = -1e30f; l_i[i] = 0.f;
        o[i] = make_float4(0.f, 0.f, 0.f, 0.f);
    }

    for (int kt = 0; kt < 32; ++kt) {
        __syncthreads();
        {
            const int row = t >> 2, c4 = t & 3;
            const float4* src = (const float4*)(qb + (size_t)(kt*64 + row) * rstride);
#pragma unroll
            for (int i = 0; i < 4; ++i) {
                float4 v = src[c4 + 4*i];
                *(float4*)&ks[row][(c4 + 4*i)*4] = v;
                const int d0 = (c4 + 4*i)*4;
                kst_ps[d0+0][row] = v.x;
                kst_ps[d0+1][row] = v.y;
                kst_ps[d0+2][row] = v.z;
                kst_ps[d0+3][row] = v.w;
            }
        }
        __syncthreads();

        float sc[16];
#pragma unroll
        for (int z = 0; z < 16; ++z) sc[z] = 0.f;
#pragma unroll 4
        for (int d4 = 0; d4 < 16; ++d4) {
            float qreg[16];
#pragma unroll
            for (int i = 0; i < 4; ++i) {
                float4 v = *(const float4*)&qs[ty*4 + i][d4*4];
                qreg[i*4+0] = v.x; qreg[i*4+1] = v.y;
                qreg[i*4+2] = v.z; qreg[i*4+3] = v.w;
            }
#pragma unroll
            for (int c = 0; c < 4; ++c) {
                float4 kv = *(const float4*)&kst_ps[d4*4 + c][tx*4];
#pragma unroll
                for (int i = 0; i < 4; ++i) {
                    const float qv = qreg[i*4 + c];
                    sc[i*4+0] = fmaf(qv, kv.x, sc[i*4+0]);
                    sc[i*4+1] = fmaf(qv, kv.y, sc[i*4+1]);
                    sc[i*4+2] = fmaf(qv, kv.z, sc[i*4+2]);
                    sc[i*4+3] = fmaf(qv, kv.w, sc[i*4+3]);
                }
            }
        }
#pragma unroll
        for (int z = 0; z < 16; ++z) sc[z] *= 0.125f;

        __syncthreads();

#pragma unroll
        for (int i = 0; i < 4; ++i) {
            float rm = fmaxf(fmaxf(sc[i*4+0], sc[i*4+1]),
                             fmaxf(sc[i*4+2], sc[i*4+3]));
            rm = fmaxf(rm, __shfl_xor(rm, 1));
            rm = fmaxf(rm, __shfl_xor(rm, 2));
            rm = fmaxf(rm, __shfl_xor(rm, 4));
            rm = fmaxf(rm, __shfl_xor(rm, 8));
            const float mnew  = fmaxf(m_i[i], rm);
            const float alpha = __expf(m_i[i] - mnew);
            m_i[i] = mnew;
            float p0 = __expf(sc[i*4+0] - mnew);
            float p1 = __expf(sc[i*4+1] - mnew);
            float p2 = __expf(sc[i*4+2] - mnew);
            float p3 = __expf(sc[i*4+3] - mnew);
            float psum = p0 + p1 + p2 + p3;
            psum += __shfl_xor(psum, 1);
            psum += __shfl_xor(psum, 2);
            psum += __shfl_xor(psum, 4);
            psum += __shfl_xor(psum, 8);
            l_i[i] = l_i[i] * alpha + psum;
            o[i].x *= alpha; o[i].y *= alpha; o[i].z *= alpha; o[i].w *= alpha;
            *(float4*)&kst_ps[ty*4 + i][tx*4] = make_float4(p0, p1, p2, p3);
        }
        __syncthreads();

#pragma unroll 4
        for (int k4 = 0; k4 < 16; ++k4) {
            float preg[16];
#pragma unroll
            for (int i = 0; i < 4; ++i) {
                float4 v = *(const float4*)&kst_ps[ty*4 + i][k4*4];
                preg[i*4+0] = v.x; preg[i*4+1] = v.y;
                preg[i*4+2] = v.z; preg[i*4+3] = v.w;
            }
#pragma unroll
            for (int c = 0; c < 4; ++c) {
                float4 vv = *(const float4*)&ks[k4*4 + c][tx*4];
#pragma unroll
                for (int i = 0; i < 4; ++i) {
                    fma4(o[i], preg[i*4 + c], vv);
                }
            }
        }
    }

    const size_t gbase = ac_base(grp);
#pragma unroll
    for (int i = 0; i < 4; ++i) {
        const float inv = 1.0f / l_i[i];
        const int q = qt*64 + ty*4 + i;
        float* dst = AC + gbase + ((size_t)((b*nseg + seg)*2048 + q)) * 256 + hg*64;
        *(float4*)(dst + tx*4) =
            make_float4(o[i].x*inv, o[i].y*inv, o[i].z*inv, o[i].w*inv);
    }
}

// ---------------------------------------------------------------------------
// Per-(group,b,head-in-group,d) sums over all positions. (unchanged, R2)
// ---------------------------------------------------------------------------
__global__ __launch_bounds__(256) void sum_kernel(
    const float* __restrict__ AC, float* __restrict__ SUMS) {
    const int bi = blockIdx.x;
    int grp, local;
    if (bi < 64)      { grp = 0; local = bi; }
    else if (bi < 96) { grp = 1; local = bi - 64; }
    else              { grp = 2; local = bi - 96; }
    const int chunks = 32 >> grp;
    const int b  = local / chunks;
    const int ch = local - b * chunks;
    const int P  = 8192 >> grp;
    const size_t base = ac_base(grp) + ((size_t)b * P + ch * 256) * 256 + threadIdx.x;
    float acc = 0.f;
    for (int p = 0; p < 256; ++p) acc += AC[base + (size_t)p * 256];
    atomicAdd(&SUMS[((grp << 1) + b) * 256 + threadIdx.x], acc);
}

// ---------------------------------------------------------------------------
// Renormalize + scatter + /3 + LayerNorm. (unchanged, R2)
// ---------------------------------------------------------------------------
__device__ __forceinline__ float block_reduce_sum(float val, float* sdata) {
    __syncthreads();
#pragma unroll
    for (int o = 32; o > 0; o >>= 1) val += __shfl_down(val, o);
    const int lane = threadIdx.x & 63, wid = threadIdx.x >> 6;
    if (lane == 0) sdata[wid] = val;
    __syncthreads();
    return sdata[0] + sdata[1] + sdata[2] + sdata[3];
}

__global__ __launch_bounds__(256) void renorm_ln_kernel(
    const float* __restrict__ AC, const float* __restrict__ SUMS,
    const float* __restrict__ gamma, const float* __restrict__ beta,
    float* __restrict__ OLN) {
    __shared__ float sdata[4];
    const int pos = blockIdx.x;
    const int b = pos >> 13;
    const int n = pos & 8191;

    float v[3];
    int dms[3];
#pragma unroll
    for (int jj = 0; jj < 3; ++jj) {
        const int dm = threadIdx.x + (jj << 8);
        dms[jj] = dm;
        const int h = dm >> 6, d = dm & 63;
        const int grp = h >> 2, hg = h & 3;
        const int r = 1 << grp;
        const int p = n & ((2048 << grp) - 1);
        float val = 0.f;
        if ((p & (r - 1)) == grp) {
            const int nseg = 4 >> grp;
            const int seg  = n >> (11 + grp);
            const int j    = (p - grp) >> grp;
            const float s  = SUMS[((grp << 1) + b) * 256 + (hg << 6) + d];
            val = AC[ac_base(grp) + ((size_t)((b*nseg + seg)*2048 + j)) * 256 + (hg << 6) + d]
                  / (3.0f * s);
        }
        v[jj] = val;
    }

    const float tot = block_reduce_sum(v[0] + v[1] + v[2], sdata);
    const float mu  = tot * (1.0f / 768.0f);
    float sq = 0.f;
#pragma unroll
    for (int jj = 0; jj < 3; ++jj) {
        const float d0 = v[jj] - mu;
        sq += d0 * d0;
    }
    const float var  = block_reduce_sum(sq, sdata) * (1.0f / 768.0f);
    const float rstd = rsqrtf(var + 1e-5f);

    float* dst = OLN + (size_t)pos * 768;
#pragma unroll
    for (int jj = 0; jj < 3; ++jj)
        dst[dms[jj]] = (v[jj] - mu) * rstd * gamma[dms[jj]] + beta[dms[jj]];
}

// ---------------------------------------------------------------------------
extern "C" void kernel_launch(void* const* d_in, const int* in_sizes, int n_in,
                              void* d_out, int out_size, void* d_ws, size_t ws_size,
                              hipStream_t stream) {
    const float* x     = (const float*)d_in[0];
    const float* w_in  = (const float*)d_in[1];
    const float* b_in  = (const float*)d_in[2];
    const float* w_out = (const float*)d_in[3];
    const float* b_out = (const float*)d_in[4];
    const float* gamma = (const float*)d_in[5];
    const float* beta  = (const float*)d_in[6];
    float* out = (float*)d_out;

    float* ws   = (float*)d_ws;
    float* Q    = ws + Q_OFF;
    float* AC   = ws + AC_OFF;
    float* SUMS = ws + SUMS_OFF;
    float* OLN  = ws + Q_OFF;   // reuse Q region (dead after attention)

    // 1) Q = x @ w_in.T + b_in   (split-bf16 MFMA)
    gemm_mfma_split<<<dim3(128, 6), 256, 0, stream>>>(x, w_in, b_in, Q);
    // 2) dilated flash attention (compact per-group output)
    attn_kernel<<<1792, 256, 0, stream>>>(Q, AC);
    // 3) per-(group,b,h,d) position sums for the x/x.sum renorm
    hipMemsetAsync(SUMS, 0, 1536 * sizeof(float), stream);
    sum_kernel<<<112, 256, 0, stream>>>(AC, SUMS);
    // 4) renorm + scatter + /3 + LayerNorm
    renorm_ln_kernel<<<B_ * N_, 256, 0, stream>>>(AC, SUMS, gamma, beta, OLN);
    // 5) out = OLN @ w_out.T + b_out   (split-bf16 MFMA)
    gemm_mfma_split<<<dim3(128, 6), 256, 0, stream>>>(OLN, w_out, b_out, out);
}

// Round 5
// 681.091 us; speedup vs baseline: 2.1915x; 1.7270x over previous
//
#include <hip/hip_runtime.h>
#include <hip/hip_bf16.h>
#include <math.h>

// Problem constants
#define B_   2
#define N_   8192
#define DM   768
#define NH   12
#define HD   64

// Workspace layout (floats): Q at 0 (reused as OLN), AC, SUMS
#define Q_OFF    0ull
#define AC_OFF   12582912ull
#define SUMS_OFF 19922944ull

typedef short bf16x8 __attribute__((ext_vector_type(8)));
typedef _Float16 f16x8 __attribute__((ext_vector_type(8)));
typedef _Float16 f16x4 __attribute__((ext_vector_type(4)));
typedef float f32x4  __attribute__((ext_vector_type(4)));

__device__ __forceinline__ size_t ac_base(int grp) {
    return 8388608ull - (8388608ull >> grp);
}

__device__ __forceinline__ unsigned short f2bf(float f) {
    __hip_bfloat16 h = __float2bfloat16(f);
    return __builtin_bit_cast(unsigned short, h);
}
__device__ __forceinline__ float bf2f(unsigned short u) {
    __hip_bfloat16 h = __builtin_bit_cast(__hip_bfloat16, u);
    return __bfloat162float(h);
}
// fp16 RNE split: f ~= hi + lo with |f - hi - lo| <= 2^-22 |f|.
__device__ __forceinline__ void split2h(float f, _Float16& h, _Float16& l) {
    h = (_Float16)f;
    l = (_Float16)(f - (float)h);
}

// XOR-chunk swizzle for [64][64] 2-byte arrays, pitch 64 (128 B row).
// 16B chunks XORed by (row&7): b128 frag reads across 16 consecutive rows
// conflict-free; staging writes spread across banks.
#define SW(row, col) ((((row) << 6)) + ((((col) >> 3) ^ ((row) & 7)) << 3) + ((col) & 7))

// ---------------------------------------------------------------------------
// Split-bf16 MFMA GEMM (NT) — exact R3-validated version (RNE-hi split).
// ---------------------------------------------------------------------------
__global__ __launch_bounds__(256) void gemm_mfma_split(
    const float* __restrict__ A, const float* __restrict__ W,
    const float* __restrict__ bias, float* __restrict__ C) {
    __shared__ unsigned short AsH[128][40];
    __shared__ unsigned short AsL[128][40];
    __shared__ unsigned short WsH[128][40];
    __shared__ unsigned short WsL[128][40];

    const int t    = threadIdx.x;
    const int lane = t & 63;
    const int wv   = t >> 6;
    const int c    = lane & 15, q = lane >> 4;
    const int mw   = (wv & 1) * 64, nw = (wv >> 1) * 64;
    const int m0   = blockIdx.x * 128, n0 = blockIdx.y * 128;

    const int srow = t >> 1;
    const int scol = (t & 1) * 16;
    const float* ap = A + (size_t)(m0 + srow) * DM + scol;
    const float* wp = W + (size_t)(n0 + srow) * DM + scol;

    f32x4 acc[4][4];
#pragma unroll
    for (int mi = 0; mi < 4; ++mi)
#pragma unroll
        for (int ni = 0; ni < 4; ++ni) {
            acc[mi][ni][0] = 0.f; acc[mi][ni][1] = 0.f;
            acc[mi][ni][2] = 0.f; acc[mi][ni][3] = 0.f;
        }

    for (int k0 = 0; k0 < DM; k0 += 32) {
        float av[16], wvv[16];
        *(float4*)&av[0]  = *(const float4*)(ap + k0);
        *(float4*)&av[4]  = *(const float4*)(ap + k0 + 4);
        *(float4*)&av[8]  = *(const float4*)(ap + k0 + 8);
        *(float4*)&av[12] = *(const float4*)(ap + k0 + 12);
        *(float4*)&wvv[0]  = *(const float4*)(wp + k0);
        *(float4*)&wvv[4]  = *(const float4*)(wp + k0 + 4);
        *(float4*)&wvv[8]  = *(const float4*)(wp + k0 + 8);
        *(float4*)&wvv[12] = *(const float4*)(wp + k0 + 12);
        __syncthreads();
#pragma unroll
        for (int i = 0; i < 16; ++i) {
            const float x = av[i];
            const unsigned short xh = f2bf(x);
            AsH[srow][scol + i] = xh;
            AsL[srow][scol + i] = f2bf(x - bf2f(xh));
            const float y = wvv[i];
            const unsigned short yh = f2bf(y);
            WsH[srow][scol + i] = yh;
            WsL[srow][scol + i] = f2bf(y - bf2f(yh));
        }
        __syncthreads();

        bf16x8 ah[4], al[4], bh[4], bl[4];
#pragma unroll
        for (int i = 0; i < 4; ++i) {
            ah[i] = *(const bf16x8*)&AsH[mw + i*16 + c][q*8];
            al[i] = *(const bf16x8*)&AsL[mw + i*16 + c][q*8];
            bh[i] = *(const bf16x8*)&WsH[nw + i*16 + c][q*8];
            bl[i] = *(const bf16x8*)&WsL[nw + i*16 + c][q*8];
        }
#pragma unroll
        for (int mi = 0; mi < 4; ++mi)
#pragma unroll
            for (int ni = 0; ni < 4; ++ni) {
                f32x4 v = acc[mi][ni];
                v = __builtin_amdgcn_mfma_f32_16x16x32_bf16(ah[mi], bl[ni], v, 0, 0, 0);
                v = __builtin_amdgcn_mfma_f32_16x16x32_bf16(al[mi], bh[ni], v, 0, 0, 0);
                v = __builtin_amdgcn_mfma_f32_16x16x32_bf16(ah[mi], bh[ni], v, 0, 0, 0);
                acc[mi][ni] = v;
            }
    }

#pragma unroll
    for (int ni = 0; ni < 4; ++ni) {
        const int col = n0 + nw + ni*16 + c;
        const float bv = bias[col];
#pragma unroll
        for (int mi = 0; mi < 4; ++mi)
#pragma unroll
            for (int r = 0; r < 4; ++r) {
                const int row = m0 + mw + mi*16 + q*4 + r;
                C[(size_t)row * DM + col] = acc[mi][ni][r] + bv;
            }
    }
}

// ---------------------------------------------------------------------------
// Split-FP16 MFMA flash attention, one (b, group, segment, head), Q=K=V.
// Same structure as R4 (layout verified to ~1e-1) but fp16 2-way split:
// operand repr error 2^-22 (vs bf16 2^-17) at identical MFMA cost.
// Q-tile 64 x K-tile 64, d=64. 4 waves; wave w owns query rows w*16..+15.
// LDS: 6 x [64][64] f16 arrays, XOR-swizzled, 48 KB -> 3 blocks/CU.
// ---------------------------------------------------------------------------
__global__ __launch_bounds__(256, 3) void attn_mfma_kernel(
    const float* __restrict__ Q, float* __restrict__ AC) {
    __shared__ _Float16 QPH[4096], QPL[4096];  // Q frags, then P
    __shared__ _Float16 KH[4096],  KL[4096];   // K row-major [key][d]
    __shared__ _Float16 VTH[4096], VTL[4096];  // K transposed [d][key]

    const int t    = threadIdx.x;
    const int lane = t & 63;
    const int w    = t >> 6;
    const int c    = lane & 15, quad = lane >> 4;

    // block -> (grp, b, seg, head, q-tile): verified mapping (R2)
    const int bi  = blockIdx.x;
    const int qt  = bi & 31;
    const int bsh = bi >> 5;
    int grp, local;
    if (bsh < 32)      { grp = 0; local = bsh; }
    else if (bsh < 48) { grp = 1; local = bsh - 32; }
    else               { grp = 2; local = bsh - 48; }
    const int nseg = 4 >> grp;
    const int sseg = 2048 << grp;
    const int r    = 1 << grp;
    const int b    = local / (nseg * 4);
    const int rem  = local - b * nseg * 4;
    const int seg  = rem >> 2;
    const int hg   = rem & 3;
    const int head = grp * 4 + hg;

    const float* qb = Q + ((size_t)(b * N_ + seg * sseg + grp)) * DM + head * HD;
    const size_t rstride = (size_t)r * DM;

    // staging coords: thread covers rows r0..r0+3 x cols c0..c0+3
    const int r0 = (t >> 4) * 4;   // 0..60
    const int c0 = (t & 15) * 4;   // 0..60

    // ---- stage Q tile and K-tile 0 ----
    {
        float fv[4][4];
#pragma unroll
        for (int i = 0; i < 4; ++i)
            *(float4*)fv[i] = *(const float4*)(qb + (size_t)(qt*64 + r0 + i) * rstride + c0);
#pragma unroll
        for (int i = 0; i < 4; ++i) {
            _Float16 hh[4], ll[4];
#pragma unroll
            for (int j = 0; j < 4; ++j) split2h(fv[i][j], hh[j], ll[j]);
            *(f16x4*)&QPH[SW(r0 + i, c0)] = (f16x4){hh[0], hh[1], hh[2], hh[3]};
            *(f16x4*)&QPL[SW(r0 + i, c0)] = (f16x4){ll[0], ll[1], ll[2], ll[3]};
        }
#pragma unroll
        for (int i = 0; i < 4; ++i)
            *(float4*)fv[i] = *(const float4*)(qb + (size_t)(r0 + i) * rstride + c0);
        _Float16 h[4][4], l[4][4];
#pragma unroll
        for (int i = 0; i < 4; ++i)
#pragma unroll
            for (int j = 0; j < 4; ++j) split2h(fv[i][j], h[i][j], l[i][j]);
#pragma unroll
        for (int i = 0; i < 4; ++i) {
            *(f16x4*)&KH[SW(r0 + i, c0)] = (f16x4){h[i][0], h[i][1], h[i][2], h[i][3]};
            *(f16x4*)&KL[SW(r0 + i, c0)] = (f16x4){l[i][0], l[i][1], l[i][2], l[i][3]};
        }
#pragma unroll
        for (int j = 0; j < 4; ++j) {
            *(f16x4*)&VTH[SW(c0 + j, r0)] = (f16x4){h[0][j], h[1][j], h[2][j], h[3][j]};
            *(f16x4*)&VTL[SW(c0 + j, r0)] = (f16x4){l[0][j], l[1][j], l[2][j], l[3][j]};
        }
    }
    __syncthreads();

    // preload loop-invariant Q A-frags (rows w*16+c, d-chunks)
    f16x8 qh[2], ql[2];
#pragma unroll
    for (int kc = 0; kc < 2; ++kc) {
        qh[kc] = *(const f16x8*)&QPH[SW(w*16 + c, kc*32 + quad*8)];
        ql[kc] = *(const f16x8*)&QPL[SW(w*16 + c, kc*32 + quad*8)];
    }
    __syncthreads();   // Q region now reusable as P

    float m_st[4], l_st[4];
    f32x4 o[4];
#pragma unroll
    for (int i = 0; i < 4; ++i) {
        m_st[i] = -1e30f; l_st[i] = 0.f;
        o[i][0] = 0.f; o[i][1] = 0.f; o[i][2] = 0.f; o[i][3] = 0.f;
    }

    for (int kt = 0; kt < 32; ++kt) {
        // prefetch next K-tile into registers (overlaps compute phase)
        float pf[4][4];
        if (kt < 31) {
#pragma unroll
            for (int i = 0; i < 4; ++i)
                *(float4*)pf[i] = *(const float4*)(qb + (size_t)((kt+1)*64 + r0 + i) * rstride + c0);
        }

        // ---- scores: S[q][k], 3-term fp16 split ----
        f32x4 s[4];
#pragma unroll
        for (int nt = 0; nt < 4; ++nt) {
            s[nt][0] = 0.f; s[nt][1] = 0.f; s[nt][2] = 0.f; s[nt][3] = 0.f;
        }
#pragma unroll
        for (int kc = 0; kc < 2; ++kc)
#pragma unroll
            for (int nt = 0; nt < 4; ++nt) {
                f16x8 bh = *(const f16x8*)&KH[SW(nt*16 + c, kc*32 + quad*8)];
                f16x8 bl = *(const f16x8*)&KL[SW(nt*16 + c, kc*32 + quad*8)];
                f32x4 v = s[nt];
                v = __builtin_amdgcn_mfma_f32_16x16x32_f16(qh[kc], bl, v, 0, 0, 0);
                v = __builtin_amdgcn_mfma_f32_16x16x32_f16(ql[kc], bh, v, 0, 0, 0);
                v = __builtin_amdgcn_mfma_f32_16x16x32_f16(qh[kc], bh, v, 0, 0, 0);
                s[nt] = v;
            }

        // ---- online softmax + P write (rows quad*4+rr, cols nt*16+c) ----
#pragma unroll
        for (int rr = 0; rr < 4; ++rr) {
            float sv0 = s[0][rr] * 0.125f, sv1 = s[1][rr] * 0.125f;
            float sv2 = s[2][rr] * 0.125f, sv3 = s[3][rr] * 0.125f;
            float rm = fmaxf(fmaxf(sv0, sv1), fmaxf(sv2, sv3));
            rm = fmaxf(rm, __shfl_xor(rm, 1));
            rm = fmaxf(rm, __shfl_xor(rm, 2));
            rm = fmaxf(rm, __shfl_xor(rm, 4));
            rm = fmaxf(rm, __shfl_xor(rm, 8));
            const float mnew  = fmaxf(m_st[rr], rm);
            const float alpha = __expf(m_st[rr] - mnew);
            m_st[rr] = mnew;
            float p0 = __expf(sv0 - mnew);
            float p1 = __expf(sv1 - mnew);
            float p2 = __expf(sv2 - mnew);
            float p3 = __expf(sv3 - mnew);
            float psum = p0 + p1 + p2 + p3;
            psum += __shfl_xor(psum, 1);
            psum += __shfl_xor(psum, 2);
            psum += __shfl_xor(psum, 4);
            psum += __shfl_xor(psum, 8);
            l_st[rr] = l_st[rr] * alpha + psum;
#pragma unroll
            for (int ntd = 0; ntd < 4; ++ntd) o[ntd][rr] *= alpha;
            const int prow = w*16 + quad*4 + rr;
            _Float16 hh, ll;
            split2h(p0, hh, ll); QPH[SW(prow, 0*16 + c)] = hh; QPL[SW(prow, 0*16 + c)] = ll;
            split2h(p1, hh, ll); QPH[SW(prow, 1*16 + c)] = hh; QPL[SW(prow, 1*16 + c)] = ll;
            split2h(p2, hh, ll); QPH[SW(prow, 2*16 + c)] = hh; QPL[SW(prow, 2*16 + c)] = ll;
            split2h(p3, hh, ll); QPH[SW(prow, 3*16 + c)] = hh; QPL[SW(prow, 3*16 + c)] = ll;
        }
        // wave-private P rows: same-wave write->read, DS pipe is in-order

        // ---- PV: O[q][d] += P V, 3-term fp16 split ----
#pragma unroll
        for (int kc = 0; kc < 2; ++kc) {
            f16x8 ph = *(const f16x8*)&QPH[SW(w*16 + c, kc*32 + quad*8)];
            f16x8 pl = *(const f16x8*)&QPL[SW(w*16 + c, kc*32 + quad*8)];
#pragma unroll
            for (int ntd = 0; ntd < 4; ++ntd) {
                f16x8 vh = *(const f16x8*)&VTH[SW(ntd*16 + c, kc*32 + quad*8)];
                f16x8 vl = *(const f16x8*)&VTL[SW(ntd*16 + c, kc*32 + quad*8)];
                f32x4 v = o[ntd];
                v = __builtin_amdgcn_mfma_f32_16x16x32_f16(ph, vl, v, 0, 0, 0);
                v = __builtin_amdgcn_mfma_f32_16x16x32_f16(pl, vh, v, 0, 0, 0);
                v = __builtin_amdgcn_mfma_f32_16x16x32_f16(ph, vh, v, 0, 0, 0);
                o[ntd] = v;
            }
        }

        // ---- stage prefetched tile ----
        if (kt < 31) {
            __syncthreads();   // all waves done reading KH/KL/VTH/VTL
            _Float16 h[4][4], l[4][4];
#pragma unroll
            for (int i = 0; i < 4; ++i)
#pragma unroll
                for (int j = 0; j < 4; ++j) split2h(pf[i][j], h[i][j], l[i][j]);
#pragma unroll
            for (int i = 0; i < 4; ++i) {
                *(f16x4*)&KH[SW(r0 + i, c0)] = (f16x4){h[i][0], h[i][1], h[i][2], h[i][3]};
                *(f16x4*)&KL[SW(r0 + i, c0)] = (f16x4){l[i][0], l[i][1], l[i][2], l[i][3]};
            }
#pragma unroll
            for (int j = 0; j < 4; ++j) {
                *(f16x4*)&VTH[SW(c0 + j, r0)] = (f16x4){h[0][j], h[1][j], h[2][j], h[3][j]};
                *(f16x4*)&VTL[SW(c0 + j, r0)] = (f16x4){l[0][j], l[1][j], l[2][j], l[3][j]};
            }
            __syncthreads();
        }
    }

    // ---- epilogue: divide by l, write compact AC ----
    const size_t gbase = ac_base(grp);
#pragma unroll
    for (int rr = 0; rr < 4; ++rr) {
        const float inv = 1.0f / l_st[rr];
        const int q = qt*64 + w*16 + quad*4 + rr;
        float* dst = AC + gbase + ((size_t)((b*nseg + seg)*2048 + q)) * 256 + hg*64;
#pragma unroll
        for (int ntd = 0; ntd < 4; ++ntd)
            dst[ntd*16 + c] = o[ntd][rr] * inv;
    }
}

// ---------------------------------------------------------------------------
// Per-(group,b,head-in-group,d) sums over all positions. (unchanged)
// ---------------------------------------------------------------------------
__global__ __launch_bounds__(256) void sum_kernel(
    const float* __restrict__ AC, float* __restrict__ SUMS) {
    const int bi = blockIdx.x;
    int grp, local;
    if (bi < 64)      { grp = 0; local = bi; }
    else if (bi < 96) { grp = 1; local = bi - 64; }
    else              { grp = 2; local = bi - 96; }
    const int chunks = 32 >> grp;
    const int b  = local / chunks;
    const int ch = local - b * chunks;
    const int P  = 8192 >> grp;
    const size_t base = ac_base(grp) + ((size_t)b * P + ch * 256) * 256 + threadIdx.x;
    float acc = 0.f;
    for (int p = 0; p < 256; ++p) acc += AC[base + (size_t)p * 256];
    atomicAdd(&SUMS[((grp << 1) + b) * 256 + threadIdx.x], acc);
}

// ---------------------------------------------------------------------------
// Renormalize + scatter + /3 + LayerNorm. (unchanged)
// ---------------------------------------------------------------------------
__device__ __forceinline__ float block_reduce_sum(float val, float* sdata) {
    __syncthreads();
#pragma unroll
    for (int o = 32; o > 0; o >>= 1) val += __shfl_down(val, o);
    const int lane = threadIdx.x & 63, wid = threadIdx.x >> 6;
    if (lane == 0) sdata[wid] = val;
    __syncthreads();
    return sdata[0] + sdata[1] + sdata[2] + sdata[3];
}

__global__ __launch_bounds__(256) void renorm_ln_kernel(
    const float* __restrict__ AC, const float* __restrict__ SUMS,
    const float* __restrict__ gamma, const float* __restrict__ beta,
    float* __restrict__ OLN) {
    __shared__ float sdata[4];
    const int pos = blockIdx.x;
    const int b = pos >> 13;
    const int n = pos & 8191;

    float v[3];
    int dms[3];
#pragma unroll
    for (int jj = 0; jj < 3; ++jj) {
        const int dm = threadIdx.x + (jj << 8);
        dms[jj] = dm;
        const int h = dm >> 6, d = dm & 63;
        const int grp = h >> 2, hg = h & 3;
        const int r = 1 << grp;
        const int p = n & ((2048 << grp) - 1);
        float val = 0.f;
        if ((p & (r - 1)) == grp) {
            const int nseg = 4 >> grp;
            const int seg  = n >> (11 + grp);
            const int j    = (p - grp) >> grp;
            const float s  = SUMS[((grp << 1) + b) * 256 + (hg << 6) + d];
            val = AC[ac_base(grp) + ((size_t)((b*nseg + seg)*2048 + j)) * 256 + (hg << 6) + d]
                  / (3.0f * s);
        }
        v[jj] = val;
    }

    const float tot = block_reduce_sum(v[0] + v[1] + v[2], sdata);
    const float mu  = tot * (1.0f / 768.0f);
    float sq = 0.f;
#pragma unroll
    for (int jj = 0; jj < 3; ++jj) {
        const float d0 = v[jj] - mu;
        sq += d0 * d0;
    }
    const float var  = block_reduce_sum(sq, sdata) * (1.0f / 768.0f);
    const float rstd = rsqrtf(var + 1e-5f);

    float* dst = OLN + (size_t)pos * 768;
#pragma unroll
    for (int jj = 0; jj < 3; ++jj)
        dst[dms[jj]] = (v[jj] - mu) * rstd * gamma[dms[jj]] + beta[dms[jj]];
}

// ---------------------------------------------------------------------------
extern "C" void kernel_launch(void* const* d_in, const int* in_sizes, int n_in,
                              void* d_out, int out_size, void* d_ws, size_t ws_size,
                              hipStream_t stream) {
    const float* x     = (const float*)d_in[0];
    const float* w_in  = (const float*)d_in[1];
    const float* b_in  = (const float*)d_in[2];
    const float* w_out = (const float*)d_in[3];
    const float* b_out = (const float*)d_in[4];
    const float* gamma = (const float*)d_in[5];
    const float* beta  = (const float*)d_in[6];
    float* out = (float*)d_out;

    float* ws   = (float*)d_ws;
    float* Q    = ws + Q_OFF;
    float* AC   = ws + AC_OFF;
    float* SUMS = ws + SUMS_OFF;
    float* OLN  = ws + Q_OFF;   // reuse Q region (dead after attention)

    // 1) Q = x @ w_in.T + b_in   (split-bf16 MFMA, R3-validated)
    gemm_mfma_split<<<dim3(128, 6), 256, 0, stream>>>(x, w_in, b_in, Q);
    // 2) dilated flash attention (split-fp16 MFMA)
    attn_mfma_kernel<<<1792, 256, 0, stream>>>(Q, AC);
    // 3) per-(group,b,h,d) position sums
    hipMemsetAsync(SUMS, 0, 1536 * sizeof(float), stream);
    sum_kernel<<<112, 256, 0, stream>>>(AC, SUMS);
    // 4) renorm + scatter + /3 + LayerNorm
    renorm_ln_kernel<<<B_ * N_, 256, 0, stream>>>(AC, SUMS, gamma, beta, OLN);
    // 5) out = OLN @ w_out.T + b_out   (split-bf16 MFMA, R3-validated)
    gemm_mfma_split<<<dim3(128, 6), 256, 0, stream>>>(OLN, w_out, b_out, out);
}

// Round 7
// 602.272 us; speedup vs baseline: 2.4783x; 1.1309x over previous
//
#include <hip/hip_runtime.h>
#include <hip/hip_bf16.h>
#include <math.h>

// Problem constants
#define B_   2
#define N_   8192
#define DM   768
#define NH   12
#define HD   64

// Workspace layout:
//   Qh (f16) at byte 0           : 12,582,912 f16  (= floats [0, 6291456))
//   Ql (f16) after it            : 12,582,912 f16  (= floats [6291456, 12582912))
//   (OLN fp32 reuses floats [0, 12582912) after attention)
//   AC  at float 12,582,912, SUMS at float 19,922,944
#define QL_ELEM_OFF 12582912ull
#define AC_OFF      12582912ull
#define SUMS_OFF    19922944ull

typedef short bf16x8 __attribute__((ext_vector_type(8)));
typedef _Float16 f16x8 __attribute__((ext_vector_type(8)));
typedef _Float16 f16x4 __attribute__((ext_vector_type(4)));
typedef float f32x4  __attribute__((ext_vector_type(4)));

__device__ __forceinline__ size_t ac_base(int grp) {
    return 8388608ull - (8388608ull >> grp);
}

__device__ __forceinline__ unsigned short f2bf(float f) {
    __hip_bfloat16 h = __float2bfloat16(f);
    return __builtin_bit_cast(unsigned short, h);
}
__device__ __forceinline__ float bf2f(unsigned short u) {
    __hip_bfloat16 h = __builtin_bit_cast(__hip_bfloat16, u);
    return __bfloat162float(h);
}
// fp16 RNE split: f ~= hi + lo with |f - hi - lo| <= 2^-22 |f|.
__device__ __forceinline__ void split2h(float f, _Float16& h, _Float16& l) {
    h = (_Float16)f;
    l = (_Float16)(f - (float)h);
}

// XOR-chunk swizzle for [64][64] 2-byte arrays, pitch 64 (128 B row).
#define SW(row, col) ((((row) << 6)) + ((((col) >> 3) ^ ((row) & 7)) << 3) + ((col) & 7))

// ---------------------------------------------------------------------------
// Split-bf16 MFMA GEMM (NT). If Ch != nullptr, epilogue writes the result as
// an fp16 RNE hi/lo split (for the attention kernel); else fp32 to C.
// ---------------------------------------------------------------------------
__global__ __launch_bounds__(256) void gemm_mfma_split(
    const float* __restrict__ A, const float* __restrict__ W,
    const float* __restrict__ bias, float* __restrict__ C,
    _Float16* __restrict__ Ch, _Float16* __restrict__ Cl) {
    __shared__ unsigned short AsH[128][40];
    __shared__ unsigned short AsL[128][40];
    __shared__ unsigned short WsH[128][40];
    __shared__ unsigned short WsL[128][40];

    const int t    = threadIdx.x;
    const int lane = t & 63;
    const int wv   = t >> 6;
    const int c    = lane & 15, q = lane >> 4;
    const int mw   = (wv & 1) * 64, nw = (wv >> 1) * 64;
    const int m0   = blockIdx.x * 128, n0 = blockIdx.y * 128;

    const int srow = t >> 1;
    const int scol = (t & 1) * 16;
    const float* ap = A + (size_t)(m0 + srow) * DM + scol;
    const float* wp = W + (size_t)(n0 + srow) * DM + scol;

    f32x4 acc[4][4];
#pragma unroll
    for (int mi = 0; mi < 4; ++mi)
#pragma unroll
        for (int ni = 0; ni < 4; ++ni) {
            acc[mi][ni][0] = 0.f; acc[mi][ni][1] = 0.f;
            acc[mi][ni][2] = 0.f; acc[mi][ni][3] = 0.f;
        }

    for (int k0 = 0; k0 < DM; k0 += 32) {
        float av[16], wvv[16];
        *(float4*)&av[0]  = *(const float4*)(ap + k0);
        *(float4*)&av[4]  = *(const float4*)(ap + k0 + 4);
        *(float4*)&av[8]  = *(const float4*)(ap + k0 + 8);
        *(float4*)&av[12] = *(const float4*)(ap + k0 + 12);
        *(float4*)&wvv[0]  = *(const float4*)(wp + k0);
        *(float4*)&wvv[4]  = *(const float4*)(wp + k0 + 4);
        *(float4*)&wvv[8]  = *(const float4*)(wp + k0 + 8);
        *(float4*)&wvv[12] = *(const float4*)(wp + k0 + 12);
        __syncthreads();
#pragma unroll
        for (int i = 0; i < 16; ++i) {
            const float x = av[i];
            const unsigned short xh = f2bf(x);
            AsH[srow][scol + i] = xh;
            AsL[srow][scol + i] = f2bf(x - bf2f(xh));
            const float y = wvv[i];
            const unsigned short yh = f2bf(y);
            WsH[srow][scol + i] = yh;
            WsL[srow][scol + i] = f2bf(y - bf2f(yh));
        }
        __syncthreads();

        bf16x8 ah[4], al[4], bh[4], bl[4];
#pragma unroll
        for (int i = 0; i < 4; ++i) {
            ah[i] = *(const bf16x8*)&AsH[mw + i*16 + c][q*8];
            al[i] = *(const bf16x8*)&AsL[mw + i*16 + c][q*8];
            bh[i] = *(const bf16x8*)&WsH[nw + i*16 + c][q*8];
            bl[i] = *(const bf16x8*)&WsL[nw + i*16 + c][q*8];
        }
#pragma unroll
        for (int mi = 0; mi < 4; ++mi)
#pragma unroll
            for (int ni = 0; ni < 4; ++ni) {
                f32x4 v = acc[mi][ni];
                v = __builtin_amdgcn_mfma_f32_16x16x32_bf16(ah[mi], bl[ni], v, 0, 0, 0);
                v = __builtin_amdgcn_mfma_f32_16x16x32_bf16(al[mi], bh[ni], v, 0, 0, 0);
                v = __builtin_amdgcn_mfma_f32_16x16x32_bf16(ah[mi], bh[ni], v, 0, 0, 0);
                acc[mi][ni] = v;
            }
    }

#pragma unroll
    for (int ni = 0; ni < 4; ++ni) {
        const int col = n0 + nw + ni*16 + c;
        const float bv = bias[col];
#pragma unroll
        for (int mi = 0; mi < 4; ++mi)
#pragma unroll
            for (int r = 0; r < 4; ++r) {
                const int row = m0 + mw + mi*16 + q*4 + r;
                const float val = acc[mi][ni][r] + bv;
                if (Ch) {
                    _Float16 hh, ll;
                    split2h(val, hh, ll);
                    Ch[(size_t)row * DM + col] = hh;
                    Cl[(size_t)row * DM + col] = ll;
                } else {
                    C[(size_t)row * DM + col] = val;
                }
            }
    }
}

// ---------------------------------------------------------------------------
// Split-FP16 MFMA flash attention, S^T orientation.
// One block per (b, group, segment, head, q-tile). Q-tile 64 x K-tile 64.
// S^T = K Q^T: C/D col = lane's query (q = w*16 + c), row = key. Softmax is
// per-lane (m, l scalars); P^T written as b64 runs (wave-private rows);
// PV as O^T = V^T P^T. Q hi/lo split precomputed by GEMM1 (Qh/Ql, fp16).
// LDS: 6 x 8 KB swizzled f16 arrays = 48 KB -> 3 blocks/CU.
// ---------------------------------------------------------------------------
__global__ __launch_bounds__(256, 3) void attn_mfma_kernel(
    const _Float16* __restrict__ Qh, const _Float16* __restrict__ Ql,
    float* __restrict__ AC) {
    __shared__ __align__(16) _Float16 KH[4096],  KL[4096];   // K row-major [key][d]
    __shared__ __align__(16) _Float16 VTH[4096], VTL[4096];  // K transposed [d][key]
    __shared__ __align__(16) _Float16 PTH[4096], PTL[4096];  // P^T as [q][k]

    const int t    = threadIdx.x;
    const int lane = t & 63;
    const int w    = t >> 6;
    const int c    = lane & 15, quad = lane >> 4;

    // block -> (grp, b, seg, head, q-tile): verified mapping (R2)
    const int bi  = blockIdx.x;
    const int qt  = bi & 31;
    const int bsh = bi >> 5;
    int grp, local;
    if (bsh < 32)      { grp = 0; local = bsh; }
    else if (bsh < 48) { grp = 1; local = bsh - 32; }
    else               { grp = 2; local = bsh - 48; }
    const int nseg = 4 >> grp;
    const int sseg = 2048 << grp;
    const int r    = 1 << grp;
    const int b    = local / (nseg * 4);
    const int rem  = local - b * nseg * 4;
    const int seg  = rem >> 2;
    const int hg   = rem & 3;
    const int head = grp * 4 + hg;

    const size_t row0 = (size_t)(b * N_ + seg * sseg + grp);
    const int hoff = head * HD;

    const int r0 = (t >> 4) * 4;   // staging rows (keys) 0..60
    const int c0 = (t & 15) * 4;   // staging cols (d)    0..60

    // ---- Q B-frags (loop-invariant): lane's query q = qt*64 + w*16 + c ----
    f16x8 qfh[2], qfl[2];
    {
        const size_t qoff = (row0 + (size_t)(qt*64 + w*16 + c) * r) * DM + hoff;
#pragma unroll
        for (int kc = 0; kc < 2; ++kc) {
            f16x8 h = *(const f16x8*)(Qh + qoff + kc*32 + quad*8);
            f16x8 l = *(const f16x8*)(Ql + qoff + kc*32 + quad*8);
            qfh[kc] = h * (_Float16)0.125f;   // fold 1/sqrt(64), exact pow2
            qfl[kc] = l * (_Float16)0.125f;
        }
    }

    // ---- stage K-tile 0 ----
    {
        f16x4 hh[4], ll[4];
#pragma unroll
        for (int i = 0; i < 4; ++i) {
            const size_t off = (row0 + (size_t)(r0 + i) * r) * DM + hoff + c0;
            hh[i] = *(const f16x4*)(Qh + off);
            ll[i] = *(const f16x4*)(Ql + off);
        }
#pragma unroll
        for (int i = 0; i < 4; ++i) {
            *(f16x4*)&KH[SW(r0 + i, c0)] = hh[i];
            *(f16x4*)&KL[SW(r0 + i, c0)] = ll[i];
        }
#pragma unroll
        for (int j = 0; j < 4; ++j) {
            *(f16x4*)&VTH[SW(c0 + j, r0)] = (f16x4){hh[0][j], hh[1][j], hh[2][j], hh[3][j]};
            *(f16x4*)&VTL[SW(c0 + j, r0)] = (f16x4){ll[0][j], ll[1][j], ll[2][j], ll[3][j]};
        }
    }
    __syncthreads();

    float m_st = -1e30f, l_st = 0.f;
    f32x4 o[4];
#pragma unroll
    for (int i = 0; i < 4; ++i) { o[i][0] = 0.f; o[i][1] = 0.f; o[i][2] = 0.f; o[i][3] = 0.f; }

    for (int kt = 0; kt < 32; ++kt) {
        // prefetch next K-tile into registers
        f16x4 nh[4], nl[4];
        if (kt < 31) {
#pragma unroll
            for (int i = 0; i < 4; ++i) {
                const size_t off = (row0 + (size_t)((kt+1)*64 + r0 + i) * r) * DM + hoff + c0;
                nh[i] = *(const f16x4*)(Qh + off);
                nl[i] = *(const f16x4*)(Ql + off);
            }
        }

        // ---- S^T[k][q]: A = K rows, B = Q^T, 3-term fp16 split ----
        f32x4 s[4];
#pragma unroll
        for (int mt = 0; mt < 4; ++mt) {
            s[mt][0] = 0.f; s[mt][1] = 0.f; s[mt][2] = 0.f; s[mt][3] = 0.f;
        }
#pragma unroll
        for (int kc = 0; kc < 2; ++kc)
#pragma unroll
            for (int mt = 0; mt < 4; ++mt) {
                f16x8 ah = *(const f16x8*)&KH[SW(mt*16 + c, kc*32 + quad*8)];
                f16x8 al = *(const f16x8*)&KL[SW(mt*16 + c, kc*32 + quad*8)];
                f32x4 v = s[mt];
                v = __builtin_amdgcn_mfma_f32_16x16x32_f16(ah, qfl[kc], v, 0, 0, 0);
                v = __builtin_amdgcn_mfma_f32_16x16x32_f16(al, qfh[kc], v, 0, 0, 0);
                v = __builtin_amdgcn_mfma_f32_16x16x32_f16(ah, qfh[kc], v, 0, 0, 0);
                s[mt] = v;
            }

        // ---- per-lane online softmax over the 64 keys of this tile ----
        // lane holds keys mt*16 + quad*4 + reg; quad-reduction via 2 shfls.
        float mloc = s[0][0];
#pragma unroll
        for (int mt = 0; mt < 4; ++mt)
#pragma unroll
            for (int rg = 0; rg < 4; ++rg) mloc = fmaxf(mloc, s[mt][rg]);
        mloc = fmaxf(mloc, __shfl_xor(mloc, 16));
        mloc = fmaxf(mloc, __shfl_xor(mloc, 32));
        const float mnew  = fmaxf(m_st, mloc);
        const float alpha = __expf(m_st - mnew);
        m_st = mnew;

        float p[16];
        float psum = 0.f;
#pragma unroll
        for (int mt = 0; mt < 4; ++mt)
#pragma unroll
            for (int rg = 0; rg < 4; ++rg) {
                const float pv = __expf(s[mt][rg] - mnew);
                p[mt*4 + rg] = pv;
                psum += pv;
            }
        psum += __shfl_xor(psum, 16);
        psum += __shfl_xor(psum, 32);
        l_st = l_st * alpha + psum;
#pragma unroll
        for (int mtd = 0; mtd < 4; ++mtd) {
            o[mtd][0] *= alpha; o[mtd][1] *= alpha;
            o[mtd][2] *= alpha; o[mtd][3] *= alpha;
        }

        // ---- P^T -> LDS (wave-private rows q = w*16+c; b64 runs) ----
#pragma unroll
        for (int mt = 0; mt < 4; ++mt) {
            f16x4 hh, ll;
#pragma unroll
            for (int rg = 0; rg < 4; ++rg) {
                _Float16 th, tl;
                split2h(p[mt*4 + rg], th, tl);
                hh[rg] = th;
                ll[rg] = tl;
            }
            *(f16x4*)&PTH[SW(w*16 + c, mt*16 + quad*4)] = hh;
            *(f16x4*)&PTL[SW(w*16 + c, mt*16 + quad*4)] = ll;
        }
        // same-wave write->read (DS pipe in-order), no barrier needed

        // ---- PV: O^T[d][q] += V^T P^T, 3-term fp16 split ----
#pragma unroll
        for (int kc = 0; kc < 2; ++kc) {
            f16x8 ph = *(const f16x8*)&PTH[SW(w*16 + c, kc*32 + quad*8)];
            f16x8 pl = *(const f16x8*)&PTL[SW(w*16 + c, kc*32 + quad*8)];
#pragma unroll
            for (int mtd = 0; mtd < 4; ++mtd) {
                f16x8 vh = *(const f16x8*)&VTH[SW(mtd*16 + c, kc*32 + quad*8)];
                f16x8 vl = *(const f16x8*)&VTL[SW(mtd*16 + c, kc*32 + quad*8)];
                f32x4 v = o[mtd];
                v = __builtin_amdgcn_mfma_f32_16x16x32_f16(vh, pl, v, 0, 0, 0);
                v = __builtin_amdgcn_mfma_f32_16x16x32_f16(vl, ph, v, 0, 0, 0);
                v = __builtin_amdgcn_mfma_f32_16x16x32_f16(vh, ph, v, 0, 0, 0);
                o[mtd] = v;
            }
        }

        // ---- stage prefetched tile ----
        if (kt < 31) {
            __syncthreads();   // all waves done reading KH/KL/VTH/VTL
#pragma unroll
            for (int i = 0; i < 4; ++i) {
                *(f16x4*)&KH[SW(r0 + i, c0)] = nh[i];
                *(f16x4*)&KL[SW(r0 + i, c0)] = nl[i];
            }
#pragma unroll
            for (int j = 0; j < 4; ++j) {
                *(f16x4*)&VTH[SW(c0 + j, r0)] = (f16x4){nh[0][j], nh[1][j], nh[2][j], nh[3][j]};
                *(f16x4*)&VTL[SW(c0 + j, r0)] = (f16x4){nl[0][j], nl[1][j], nl[2][j], nl[3][j]};
            }
            __syncthreads();
        }
    }

    // ---- epilogue: O^T C-layout -> AC rows; lane q = qt*64+w*16+c ----
    const size_t gbase = ac_base(grp);
    const float inv = 1.0f / l_st;
    const int qrow = qt*64 + w*16 + c;
    float* dst = AC + gbase + ((size_t)((b*nseg + seg)*2048 + qrow)) * 256 + hg*64;
#pragma unroll
    for (int mtd = 0; mtd < 4; ++mtd) {
        float4 v = make_float4(o[mtd][0]*inv, o[mtd][1]*inv,
                               o[mtd][2]*inv, o[mtd][3]*inv);
        *(float4*)(dst + mtd*16 + quad*4) = v;
    }
}

// ---------------------------------------------------------------------------
// Per-(group,b,head-in-group,d) sums over all positions. (unchanged)
// ---------------------------------------------------------------------------
__global__ __launch_bounds__(256) void sum_kernel(
    const float* __restrict__ AC, float* __restrict__ SUMS) {
    const int bi = blockIdx.x;
    int grp, local;
    if (bi < 64)      { grp = 0; local = bi; }
    else if (bi < 96) { grp = 1; local = bi - 64; }
    else              { grp = 2; local = bi - 96; }
    const int chunks = 32 >> grp;
    const int b  = local / chunks;
    const int ch = local - b * chunks;
    const int P  = 8192 >> grp;
    const size_t base = ac_base(grp) + ((size_t)b * P + ch * 256) * 256 + threadIdx.x;
    float acc = 0.f;
    for (int p = 0; p < 256; ++p) acc += AC[base + (size_t)p * 256];
    atomicAdd(&SUMS[((grp << 1) + b) * 256 + threadIdx.x], acc);
}

// ---------------------------------------------------------------------------
// Renormalize + scatter + /3 + LayerNorm. (unchanged)
// ---------------------------------------------------------------------------
__device__ __forceinline__ float block_reduce_sum(float val, float* sdata) {
    __syncthreads();
#pragma unroll
    for (int o = 32; o > 0; o >>= 1) val += __shfl_down(val, o);
    const int lane = threadIdx.x & 63, wid = threadIdx.x >> 6;
    if (lane == 0) sdata[wid] = val;
    __syncthreads();
    return sdata[0] + sdata[1] + sdata[2] + sdata[3];
}

__global__ __launch_bounds__(256) void renorm_ln_kernel(
    const float* __restrict__ AC, const float* __restrict__ SUMS,
    const float* __restrict__ gamma, const float* __restrict__ beta,
    float* __restrict__ OLN) {
    __shared__ float sdata[4];
    const int pos = blockIdx.x;
    const int b = pos >> 13;
    const int n = pos & 8191;

    float v[3];
    int dms[3];
#pragma unroll
    for (int jj = 0; jj < 3; ++jj) {
        const int dm = threadIdx.x + (jj << 8);
        dms[jj] = dm;
        const int h = dm >> 6, d = dm & 63;
        const int grp = h >> 2, hg = h & 3;
        const int r = 1 << grp;
        const int p = n & ((2048 << grp) - 1);
        float val = 0.f;
        if ((p & (r - 1)) == grp) {
            const int nseg = 4 >> grp;
            const int seg  = n >> (11 + grp);
            const int j    = (p - grp) >> grp;
            const float s  = SUMS[((grp << 1) + b) * 256 + (hg << 6) + d];
            val = AC[ac_base(grp) + ((size_t)((b*nseg + seg)*2048 + j)) * 256 + (hg << 6) + d]
                  / (3.0f * s);
        }
        v[jj] = val;
    }

    const float tot = block_reduce_sum(v[0] + v[1] + v[2], sdata);
    const float mu  = tot * (1.0f / 768.0f);
    float sq = 0.f;
#pragma unroll
    for (int jj = 0; jj < 3; ++jj) {
        const float d0 = v[jj] - mu;
        sq += d0 * d0;
    }
    const float var  = block_reduce_sum(sq, sdata) * (1.0f / 768.0f);
    const float rstd = rsqrtf(var + 1e-5f);

    float* dst = OLN + (size_t)pos * 768;
#pragma unroll
    for (int jj = 0; jj < 3; ++jj)
        dst[dms[jj]] = (v[jj] - mu) * rstd * gamma[dms[jj]] + beta[dms[jj]];
}

// ---------------------------------------------------------------------------
extern "C" void kernel_launch(void* const* d_in, const int* in_sizes, int n_in,
                              void* d_out, int out_size, void* d_ws, size_t ws_size,
                              hipStream_t stream) {
    const float* x     = (const float*)d_in[0];
    const float* w_in  = (const float*)d_in[1];
    const float* b_in  = (const float*)d_in[2];
    const float* w_out = (const float*)d_in[3];
    const float* b_out = (const float*)d_in[4];
    const float* gamma = (const float*)d_in[5];
    const float* beta  = (const float*)d_in[6];
    float* out = (float*)d_out;

    float* ws   = (float*)d_ws;
    _Float16* Qh = (_Float16*)ws;                 // fp16 hi, 12.58M elems
    _Float16* Ql = (_Float16*)ws + QL_ELEM_OFF;   // fp16 lo
    float* AC   = ws + AC_OFF;
    float* SUMS = ws + SUMS_OFF;
    float* OLN  = ws;   // reuses Qh/Ql region (dead after attention)

    // 1) Q = x @ w_in.T + b_in, written as fp16 hi/lo split
    gemm_mfma_split<<<dim3(128, 6), 256, 0, stream>>>(x, w_in, b_in, nullptr, Qh, Ql);
    // 2) dilated flash attention (split-fp16 MFMA, S^T orientation)
    attn_mfma_kernel<<<1792, 256, 0, stream>>>(Qh, Ql, AC);
    // 3) per-(group,b,h,d) position sums
    (void)hipMemsetAsync(SUMS, 0, 1536 * sizeof(float), stream);
    sum_kernel<<<112, 256, 0, stream>>>(AC, SUMS);
    // 4) renorm + scatter + /3 + LayerNorm
    renorm_ln_kernel<<<B_ * N_, 256, 0, stream>>>(AC, SUMS, gamma, beta, OLN);
    // 5) out = OLN @ w_out.T + b_out (fp32 epilogue)
    gemm_mfma_split<<<dim3(128, 6), 256, 0, stream>>>(OLN, w_out, b_out, out,
                                                      nullptr, nullptr);
}

// Round 8
// 571.223 us; speedup vs baseline: 2.6130x; 1.0544x over previous
//
#include <hip/hip_runtime.h>
#include <hip/hip_bf16.h>
#include <math.h>

// Problem constants
#define B_   2
#define N_   8192
#define DM   768
#define NH   12
#define HD   64

// Workspace layout:
//   Qh (f16) at byte 0           : 12,582,912 f16  (= floats [0, 6291456))
//   Ql (f16) after it            : 12,582,912 f16
//   (OLN fp32 reuses floats [0, 12582912) after attention)
//   AC  at float 12,582,912, SUMS at float 19,922,944
#define QL_ELEM_OFF 12582912ull
#define AC_OFF      12582912ull
#define SUMS_OFF    19922944ull

typedef short bf16x8 __attribute__((ext_vector_type(8)));
typedef _Float16 f16x8 __attribute__((ext_vector_type(8)));
typedef _Float16 f16x4 __attribute__((ext_vector_type(4)));
typedef float f32x4  __attribute__((ext_vector_type(4)));

__device__ __forceinline__ size_t ac_base(int grp) {
    return 8388608ull - (8388608ull >> grp);
}

__device__ __forceinline__ unsigned short f2bf(float f) {
    __hip_bfloat16 h = __float2bfloat16(f);
    return __builtin_bit_cast(unsigned short, h);
}
__device__ __forceinline__ float bf2f(unsigned short u) {
    __hip_bfloat16 h = __builtin_bit_cast(__hip_bfloat16, u);
    return __bfloat162float(h);
}
// fp16 RNE split: f ~= hi + lo with |f - hi - lo| <= 2^-22 |f|.
__device__ __forceinline__ void split2h(float f, _Float16& h, _Float16& l) {
    h = (_Float16)f;
    l = (_Float16)(f - (float)h);
}

// XOR-chunk swizzle for 2-byte arrays, pitch 64 elements (128 B row).
// 16B chunks XORed by (row&7): b128 frag reads conflict-free.
#define SW(row, col) ((((row) << 6)) + ((((col) >> 3) ^ ((row) & 7)) << 3) + ((col) & 7))

// ---------------------------------------------------------------------------
// Split-bf16 MFMA GEMM (NT). If Ch != nullptr, epilogue writes the result as
// an fp16 RNE hi/lo split (for the attention kernel); else fp32 to C.
// ---------------------------------------------------------------------------
__global__ __launch_bounds__(256) void gemm_mfma_split(
    const float* __restrict__ A, const float* __restrict__ W,
    const float* __restrict__ bias, float* __restrict__ C,
    _Float16* __restrict__ Ch, _Float16* __restrict__ Cl) {
    __shared__ unsigned short AsH[128][40];
    __shared__ unsigned short AsL[128][40];
    __shared__ unsigned short WsH[128][40];
    __shared__ unsigned short WsL[128][40];

    const int t    = threadIdx.x;
    const int lane = t & 63;
    const int wv   = t >> 6;
    const int c    = lane & 15, q = lane >> 4;
    const int mw   = (wv & 1) * 64, nw = (wv >> 1) * 64;
    const int m0   = blockIdx.x * 128, n0 = blockIdx.y * 128;

    const int srow = t >> 1;
    const int scol = (t & 1) * 16;
    const float* ap = A + (size_t)(m0 + srow) * DM + scol;
    const float* wp = W + (size_t)(n0 + srow) * DM + scol;

    f32x4 acc[4][4];
#pragma unroll
    for (int mi = 0; mi < 4; ++mi)
#pragma unroll
        for (int ni = 0; ni < 4; ++ni) {
            acc[mi][ni][0] = 0.f; acc[mi][ni][1] = 0.f;
            acc[mi][ni][2] = 0.f; acc[mi][ni][3] = 0.f;
        }

    for (int k0 = 0; k0 < DM; k0 += 32) {
        float av[16], wvv[16];
        *(float4*)&av[0]  = *(const float4*)(ap + k0);
        *(float4*)&av[4]  = *(const float4*)(ap + k0 + 4);
        *(float4*)&av[8]  = *(const float4*)(ap + k0 + 8);
        *(float4*)&av[12] = *(const float4*)(ap + k0 + 12);
        *(float4*)&wvv[0]  = *(const float4*)(wp + k0);
        *(float4*)&wvv[4]  = *(const float4*)(wp + k0 + 4);
        *(float4*)&wvv[8]  = *(const float4*)(wp + k0 + 8);
        *(float4*)&wvv[12] = *(const float4*)(wp + k0 + 12);
        __syncthreads();
#pragma unroll
        for (int i = 0; i < 16; ++i) {
            const float x = av[i];
            const unsigned short xh = f2bf(x);
            AsH[srow][scol + i] = xh;
            AsL[srow][scol + i] = f2bf(x - bf2f(xh));
            const float y = wvv[i];
            const unsigned short yh = f2bf(y);
            WsH[srow][scol + i] = yh;
            WsL[srow][scol + i] = f2bf(y - bf2f(yh));
        }
        __syncthreads();

        bf16x8 ah[4], al[4], bh[4], bl[4];
#pragma unroll
        for (int i = 0; i < 4; ++i) {
            ah[i] = *(const bf16x8*)&AsH[mw + i*16 + c][q*8];
            al[i] = *(const bf16x8*)&AsL[mw + i*16 + c][q*8];
            bh[i] = *(const bf16x8*)&WsH[nw + i*16 + c][q*8];
            bl[i] = *(const bf16x8*)&WsL[nw + i*16 + c][q*8];
        }
#pragma unroll
        for (int mi = 0; mi < 4; ++mi)
#pragma unroll
            for (int ni = 0; ni < 4; ++ni) {
                f32x4 v = acc[mi][ni];
                v = __builtin_amdgcn_mfma_f32_16x16x32_bf16(ah[mi], bl[ni], v, 0, 0, 0);
                v = __builtin_amdgcn_mfma_f32_16x16x32_bf16(al[mi], bh[ni], v, 0, 0, 0);
                v = __builtin_amdgcn_mfma_f32_16x16x32_bf16(ah[mi], bh[ni], v, 0, 0, 0);
                acc[mi][ni] = v;
            }
    }

#pragma unroll
    for (int ni = 0; ni < 4; ++ni) {
        const int col = n0 + nw + ni*16 + c;
        const float bv = bias[col];
#pragma unroll
        for (int mi = 0; mi < 4; ++mi)
#pragma unroll
            for (int r = 0; r < 4; ++r) {
                const int row = m0 + mw + mi*16 + q*4 + r;
                const float val = acc[mi][ni][r] + bv;
                if (Ch) {
                    _Float16 hh, ll;
                    split2h(val, hh, ll);
                    Ch[(size_t)row * DM + col] = hh;
                    Cl[(size_t)row * DM + col] = ll;
                } else {
                    C[(size_t)row * DM + col] = val;
                }
            }
    }
}

// ---------------------------------------------------------------------------
// Split-FP16 MFMA flash attention, S^T orientation, 128-query blocks.
// One block per (b, group, segment, head, 128-q tile). K-tile 64.
// Wave w owns queries w*32..+31 as two 16-col tiles (jt); per-lane softmax
// (query = C/D col = lane&15). S^T = K Q^T; P^T -> LDS (wave-private rows,
// b64 even-banked); O^T = V^T P^T. K/V^T staged once per K-tile and reused
// by all 128 queries (2x the R7 reuse). LDS 64 KB -> 2 blocks/CU.
// ---------------------------------------------------------------------------
__global__ __launch_bounds__(256, 2) void attn_mfma_kernel(
    const _Float16* __restrict__ Qh, const _Float16* __restrict__ Ql,
    float* __restrict__ AC) {
    __shared__ __align__(16) _Float16 KH[4096],  KL[4096];   // K row-major [key][d]
    __shared__ __align__(16) _Float16 VTH[4096], VTL[4096];  // K transposed [d][key]
    __shared__ __align__(16) _Float16 PTH[8192], PTL[8192];  // P^T as [q(128)][k(64)]

    const int t    = threadIdx.x;
    const int lane = t & 63;
    const int w    = t >> 6;
    const int c    = lane & 15, quad = lane >> 4;

    // block -> (grp, b, seg, head, q-tile)
    const int bi  = blockIdx.x;
    const int qt  = bi & 15;           // 16 tiles of 128 queries per 2048
    const int bsh = bi >> 4;
    int grp, local;
    if (bsh < 32)      { grp = 0; local = bsh; }
    else if (bsh < 48) { grp = 1; local = bsh - 32; }
    else               { grp = 2; local = bsh - 48; }
    const int nseg = 4 >> grp;
    const int sseg = 2048 << grp;
    const int r    = 1 << grp;
    const int b    = local / (nseg * 4);
    const int rem  = local - b * nseg * 4;
    const int seg  = rem >> 2;
    const int hg   = rem & 3;
    const int head = grp * 4 + hg;

    const size_t row0 = (size_t)(b * N_ + seg * sseg + grp);
    const int hoff = head * HD;

    const int r0 = (t >> 4) * 4;   // staging rows (keys) 0..60
    const int c0 = (t & 15) * 4;   // staging cols (d)    0..60

    // ---- Q B-frags (loop-invariant): queries qt*128 + w*32 + jt*16 + c ----
    f16x8 qfh[2][2], qfl[2][2];   // [jt][kc]
#pragma unroll
    for (int jt = 0; jt < 2; ++jt) {
        const int qrow = qt*128 + w*32 + jt*16 + c;
        const size_t qoff = (row0 + (size_t)qrow * r) * DM + hoff;
#pragma unroll
        for (int kc = 0; kc < 2; ++kc) {
            f16x8 h = *(const f16x8*)(Qh + qoff + kc*32 + quad*8);
            f16x8 l = *(const f16x8*)(Ql + qoff + kc*32 + quad*8);
            qfh[jt][kc] = h * (_Float16)0.125f;   // fold 1/sqrt(64), exact pow2
            qfl[jt][kc] = l * (_Float16)0.125f;
        }
    }

    // ---- stage K-tile 0 ----
    {
        f16x4 hh[4], ll[4];
#pragma unroll
        for (int i = 0; i < 4; ++i) {
            const size_t off = (row0 + (size_t)(r0 + i) * r) * DM + hoff + c0;
            hh[i] = *(const f16x4*)(Qh + off);
            ll[i] = *(const f16x4*)(Ql + off);
        }
#pragma unroll
        for (int i = 0; i < 4; ++i) {
            *(f16x4*)&KH[SW(r0 + i, c0)] = hh[i];
            *(f16x4*)&KL[SW(r0 + i, c0)] = ll[i];
        }
#pragma unroll
        for (int j = 0; j < 4; ++j) {
            *(f16x4*)&VTH[SW(c0 + j, r0)] = (f16x4){hh[0][j], hh[1][j], hh[2][j], hh[3][j]};
            *(f16x4*)&VTL[SW(c0 + j, r0)] = (f16x4){ll[0][j], ll[1][j], ll[2][j], ll[3][j]};
        }
    }
    __syncthreads();

    float m_st[2] = {-1e30f, -1e30f};
    float l_st[2] = {0.f, 0.f};
    f32x4 o[2][4];
#pragma unroll
    for (int jt = 0; jt < 2; ++jt)
#pragma unroll
        for (int i = 0; i < 4; ++i) {
            o[jt][i][0] = 0.f; o[jt][i][1] = 0.f;
            o[jt][i][2] = 0.f; o[jt][i][3] = 0.f;
        }

    for (int kt = 0; kt < 32; ++kt) {
        // prefetch next K-tile into registers
        f16x4 nh[4], nl[4];
        if (kt < 31) {
#pragma unroll
            for (int i = 0; i < 4; ++i) {
                const size_t off = (row0 + (size_t)((kt+1)*64 + r0 + i) * r) * DM + hoff + c0;
                nh[i] = *(const f16x4*)(Qh + off);
                nl[i] = *(const f16x4*)(Ql + off);
            }
        }

        // ---- S^T[k][q]: A = K rows (shared across jt), B = Q^T ----
        f32x4 s[2][4];
#pragma unroll
        for (int jt = 0; jt < 2; ++jt)
#pragma unroll
            for (int mt = 0; mt < 4; ++mt) {
                s[jt][mt][0] = 0.f; s[jt][mt][1] = 0.f;
                s[jt][mt][2] = 0.f; s[jt][mt][3] = 0.f;
            }
#pragma unroll
        for (int kc = 0; kc < 2; ++kc)
#pragma unroll
            for (int mt = 0; mt < 4; ++mt) {
                f16x8 ah = *(const f16x8*)&KH[SW(mt*16 + c, kc*32 + quad*8)];
                f16x8 al = *(const f16x8*)&KL[SW(mt*16 + c, kc*32 + quad*8)];
#pragma unroll
                for (int jt = 0; jt < 2; ++jt) {
                    f32x4 v = s[jt][mt];
                    v = __builtin_amdgcn_mfma_f32_16x16x32_f16(ah, qfl[jt][kc], v, 0, 0, 0);
                    v = __builtin_amdgcn_mfma_f32_16x16x32_f16(al, qfh[jt][kc], v, 0, 0, 0);
                    v = __builtin_amdgcn_mfma_f32_16x16x32_f16(ah, qfh[jt][kc], v, 0, 0, 0);
                    s[jt][mt] = v;
                }
            }

        // ---- per-lane online softmax (independent per jt) + P^T write ----
#pragma unroll
        for (int jt = 0; jt < 2; ++jt) {
            float mloc = s[jt][0][0];
#pragma unroll
            for (int mt = 0; mt < 4; ++mt)
#pragma unroll
                for (int rg = 0; rg < 4; ++rg) mloc = fmaxf(mloc, s[jt][mt][rg]);
            mloc = fmaxf(mloc, __shfl_xor(mloc, 16));
            mloc = fmaxf(mloc, __shfl_xor(mloc, 32));
            const float mnew  = fmaxf(m_st[jt], mloc);
            const float alpha = __expf(m_st[jt] - mnew);
            m_st[jt] = mnew;

            float psum = 0.f;
            const int prow = w*32 + jt*16 + c;
#pragma unroll
            for (int mt = 0; mt < 4; ++mt) {
                f16x4 hh, ll;
#pragma unroll
                for (int rg = 0; rg < 4; ++rg) {
                    const float pv = __expf(s[jt][mt][rg] - mnew);
                    psum += pv;
                    _Float16 th, tl;
                    split2h(pv, th, tl);
                    hh[rg] = th;
                    ll[rg] = tl;
                }
                *(f16x4*)&PTH[SW(prow, mt*16 + quad*4)] = hh;
                *(f16x4*)&PTL[SW(prow, mt*16 + quad*4)] = ll;
            }
            psum += __shfl_xor(psum, 16);
            psum += __shfl_xor(psum, 32);
            l_st[jt] = l_st[jt] * alpha + psum;
#pragma unroll
            for (int mtd = 0; mtd < 4; ++mtd) {
                o[jt][mtd][0] *= alpha; o[jt][mtd][1] *= alpha;
                o[jt][mtd][2] *= alpha; o[jt][mtd][3] *= alpha;
            }
        }
        // wave-private P^T rows: same-wave write->read, no barrier needed

        // ---- PV: O^T[d][q] += V^T P^T (V^T frags shared across jt) ----
#pragma unroll
        for (int kc = 0; kc < 2; ++kc) {
            f16x8 ph[2], pl[2];
#pragma unroll
            for (int jt = 0; jt < 2; ++jt) {
                ph[jt] = *(const f16x8*)&PTH[SW(w*32 + jt*16 + c, kc*32 + quad*8)];
                pl[jt] = *(const f16x8*)&PTL[SW(w*32 + jt*16 + c, kc*32 + quad*8)];
            }
#pragma unroll
            for (int mtd = 0; mtd < 4; ++mtd) {
                f16x8 vh = *(const f16x8*)&VTH[SW(mtd*16 + c, kc*32 + quad*8)];
                f16x8 vl = *(const f16x8*)&VTL[SW(mtd*16 + c, kc*32 + quad*8)];
#pragma unroll
                for (int jt = 0; jt < 2; ++jt) {
                    f32x4 v = o[jt][mtd];
                    v = __builtin_amdgcn_mfma_f32_16x16x32_f16(vh, pl[jt], v, 0, 0, 0);
                    v = __builtin_amdgcn_mfma_f32_16x16x32_f16(vl, ph[jt], v, 0, 0, 0);
                    v = __builtin_amdgcn_mfma_f32_16x16x32_f16(vh, ph[jt], v, 0, 0, 0);
                    o[jt][mtd] = v;
                }
            }
        }

        // ---- stage prefetched tile ----
        if (kt < 31) {
            __syncthreads();   // all waves done reading KH/KL/VTH/VTL
#pragma unroll
            for (int i = 0; i < 4; ++i) {
                *(f16x4*)&KH[SW(r0 + i, c0)] = nh[i];
                *(f16x4*)&KL[SW(r0 + i, c0)] = nl[i];
            }
#pragma unroll
            for (int j = 0; j < 4; ++j) {
                *(f16x4*)&VTH[SW(c0 + j, r0)] = (f16x4){nh[0][j], nh[1][j], nh[2][j], nh[3][j]};
                *(f16x4*)&VTL[SW(c0 + j, r0)] = (f16x4){nl[0][j], nl[1][j], nl[2][j], nl[3][j]};
            }
            __syncthreads();
        }
    }

    // ---- epilogue: O^T C-layout -> AC rows ----
    const size_t gbase = ac_base(grp);
#pragma unroll
    for (int jt = 0; jt < 2; ++jt) {
        const float inv = 1.0f / l_st[jt];
        const int qrow = qt*128 + w*32 + jt*16 + c;
        float* dst = AC + gbase + ((size_t)((b*nseg + seg)*2048 + qrow)) * 256 + hg*64;
#pragma unroll
        for (int mtd = 0; mtd < 4; ++mtd) {
            float4 v = make_float4(o[jt][mtd][0]*inv, o[jt][mtd][1]*inv,
                                   o[jt][mtd][2]*inv, o[jt][mtd][3]*inv);
            *(float4*)(dst + mtd*16 + quad*4) = v;
        }
    }
}

// ---------------------------------------------------------------------------
// Per-(group,b,head-in-group,d) sums over all positions. (unchanged)
// ---------------------------------------------------------------------------
__global__ __launch_bounds__(256) void sum_kernel(
    const float* __restrict__ AC, float* __restrict__ SUMS) {
    const int bi = blockIdx.x;
    int grp, local;
    if (bi < 64)      { grp = 0; local = bi; }
    else if (bi < 96) { grp = 1; local = bi - 64; }
    else              { grp = 2; local = bi - 96; }
    const int chunks = 32 >> grp;
    const int b  = local / chunks;
    const int ch = local - b * chunks;
    const int P  = 8192 >> grp;
    const size_t base = ac_base(grp) + ((size_t)b * P + ch * 256) * 256 + threadIdx.x;
    float acc = 0.f;
    for (int p = 0; p < 256; ++p) acc += AC[base + (size_t)p * 256];
    atomicAdd(&SUMS[((grp << 1) + b) * 256 + threadIdx.x], acc);
}

// ---------------------------------------------------------------------------
// Renormalize + scatter + /3 + LayerNorm. (unchanged)
// ---------------------------------------------------------------------------
__device__ __forceinline__ float block_reduce_sum(float val, float* sdata) {
    __syncthreads();
#pragma unroll
    for (int o = 32; o > 0; o >>= 1) val += __shfl_down(val, o);
    const int lane = threadIdx.x & 63, wid = threadIdx.x >> 6;
    if (lane == 0) sdata[wid] = val;
    __syncthreads();
    return sdata[0] + sdata[1] + sdata[2] + sdata[3];
}

__global__ __launch_bounds__(256) void renorm_ln_kernel(
    const float* __restrict__ AC, const float* __restrict__ SUMS,
    const float* __restrict__ gamma, const float* __restrict__ beta,
    float* __restrict__ OLN) {
    __shared__ float sdata[4];
    const int pos = blockIdx.x;
    const int b = pos >> 13;
    const int n = pos & 8191;

    float v[3];
    int dms[3];
#pragma unroll
    for (int jj = 0; jj < 3; ++jj) {
        const int dm = threadIdx.x + (jj << 8);
        dms[jj] = dm;
        const int h = dm >> 6, d = dm & 63;
        const int grp = h >> 2, hg = h & 3;
        const int r = 1 << grp;
        const int p = n & ((2048 << grp) - 1);
        float val = 0.f;
        if ((p & (r - 1)) == grp) {
            const int nseg = 4 >> grp;
            const int seg  = n >> (11 + grp);
            const int j    = (p - grp) >> grp;
            const float s  = SUMS[((grp << 1) + b) * 256 + (hg << 6) + d];
            val = AC[ac_base(grp) + ((size_t)((b*nseg + seg)*2048 + j)) * 256 + (hg << 6) + d]
                  / (3.0f * s);
        }
        v[jj] = val;
    }

    const float tot = block_reduce_sum(v[0] + v[1] + v[2], sdata);
    const float mu  = tot * (1.0f / 768.0f);
    float sq = 0.f;
#pragma unroll
    for (int jj = 0; jj < 3; ++jj) {
        const float d0 = v[jj] - mu;
        sq += d0 * d0;
    }
    const float var  = block_reduce_sum(sq, sdata) * (1.0f / 768.0f);
    const float rstd = rsqrtf(var + 1e-5f);

    float* dst = OLN + (size_t)pos * 768;
#pragma unroll
    for (int jj = 0; jj < 3; ++jj)
        dst[dms[jj]] = (v[jj] - mu) * rstd * gamma[dms[jj]] + beta[dms[jj]];
}

// ---------------------------------------------------------------------------
extern "C" void kernel_launch(void* const* d_in, const int* in_sizes, int n_in,
                              void* d_out, int out_size, void* d_ws, size_t ws_size,
                              hipStream_t stream) {
    const float* x     = (const float*)d_in[0];
    const float* w_in  = (const float*)d_in[1];
    const float* b_in  = (const float*)d_in[2];
    const float* w_out = (const float*)d_in[3];
    const float* b_out = (const float*)d_in[4];
    const float* gamma = (const float*)d_in[5];
    const float* beta  = (const float*)d_in[6];
    float* out = (float*)d_out;

    float* ws   = (float*)d_ws;
    _Float16* Qh = (_Float16*)ws;                 // fp16 hi, 12.58M elems
    _Float16* Ql = (_Float16*)ws + QL_ELEM_OFF;   // fp16 lo
    float* AC   = ws + AC_OFF;
    float* SUMS = ws + SUMS_OFF;
    float* OLN  = ws;   // reuses Qh/Ql region (dead after attention)

    // 1) Q = x @ w_in.T + b_in, written as fp16 hi/lo split
    gemm_mfma_split<<<dim3(128, 6), 256, 0, stream>>>(x, w_in, b_in, nullptr, Qh, Ql);
    // 2) dilated flash attention (split-fp16 MFMA, S^T, 128-q blocks)
    attn_mfma_kernel<<<896, 256, 0, stream>>>(Qh, Ql, AC);
    // 3) per-(group,b,h,d) position sums
    (void)hipMemsetAsync(SUMS, 0, 1536 * sizeof(float), stream);
    sum_kernel<<<112, 256, 0, stream>>>(AC, SUMS);
    // 4) renorm + scatter + /3 + LayerNorm
    renorm_ln_kernel<<<B_ * N_, 256, 0, stream>>>(AC, SUMS, gamma, beta, OLN);
    // 5) out = OLN @ w_out.T + b_out (fp32 epilogue)
    gemm_mfma_split<<<dim3(128, 6), 256, 0, stream>>>(OLN, w_out, b_out, out,
                                                      nullptr, nullptr);
}